// Round 5
// baseline (726.474 us; speedup 1.0000x reference)
//
#include <hip/hip_runtime.h>
#include <stdint.h>

// Problem constants (B=256, L=2048, H=64, TE=64)
#define NB 256
#define NL 2048

typedef __attribute__((ext_vector_type(8))) short short8;
typedef __attribute__((ext_vector_type(4))) float f32x4;
#define MFMA16(a,b,c) __builtin_amdgcn_mfma_f32_16x16x32_bf16(a,b,c,0,0,0)

// ---------- bf16 helpers (manual, RNE) ----------
static __device__ __forceinline__ unsigned short f2bf(float f) {
    union { float f; uint32_t u; } v; v.f = f;
    uint32_t u = v.u;
    uint32_t r = u + 0x7fffu + ((u >> 16) & 1u);
    return (unsigned short)(r >> 16);
}
static __device__ __forceinline__ float bflo(uint32_t u) {
    union { uint32_t u; float f; } v; v.u = u << 16; return v.f;
}
static __device__ __forceinline__ float bfhi(uint32_t u) {
    union { uint32_t u; float f; } v; v.u = u & 0xffff0000u; return v.f;
}
static __device__ __forceinline__ uint32_t pack2(float lo, float hi) {
    return ((uint32_t)f2bf(hi) << 16) | (uint32_t)f2bf(lo);
}
static __device__ __forceinline__ short8 frag8(const float* p) {
    short8 r;
#pragma unroll
    for (int j = 0; j < 8; ++j) r[j] = (short)f2bf(p[j]);
    return r;
}

// =====================================================================
// kernel 1: MFMA prep — time-MLP + proj + gates -> packed (a,b)
// block = 256 thr (4 waves), 4 chunks of 64 positions; grid = 8*Bg
// LDS: s_inp 18432 + union(te1+tenc+xa 23552 | ab 33280) = 51712 B -> 3 blk/CU
// =====================================================================
union PrepU {
    struct {
        unsigned short te1[64*72];    //  9216 B
        unsigned short tenc[64*72];   //  9216 B
        unsigned short xa[64*40];     //  5120 B
    } p;
    uint32_t ab[2][64*65];            // 33280 B (packed a|b, stride 65)
};

__global__ __launch_bounds__(256, 3) void prep_kernel(
    const float* __restrict__ x, const float* __restrict__ t,
    const float* __restrict__ mtok,
    const float* __restrict__ te_w1, const float* __restrict__ te_b1,
    const float* __restrict__ te_w2, const float* __restrict__ te_b2,
    const float* __restrict__ fpw, const float* __restrict__ fpb,
    const float* __restrict__ bpw, const float* __restrict__ bpb,
    const float* __restrict__ fwz, const float* __restrict__ fbz,
    const float* __restrict__ fwh, const float* __restrict__ fbh,
    const float* __restrict__ bwz, const float* __restrict__ bbz,
    const float* __restrict__ bwh, const float* __restrict__ bbh,
    int b0,
    uint32_t* __restrict__ abf,              // [Bg*64, L] packed (a lo, b hi)
    uint32_t* __restrict__ abb)
{
    __shared__ __align__(16) PrepU u;
    __shared__ __align__(16) unsigned short s_inp[2][64*72];  // 18432 B

    const int tid = threadIdx.x;
    const int w   = tid >> 6;     // wave 0..3
    const int l   = tid & 63;
    const int lq  = l >> 4;       // quad
    const int ln  = l & 15;

    // ---- weight B-fragments (once per block) ----
    short8 bte[2];
    {
        const float* row = te_w2 + (w*16 + ln)*64;
#pragma unroll
        for (int ks = 0; ks < 2; ++ks) bte[ks] = frag8(row + lq*8 + ks*32);
    }
    short8 bpj[2][3];
#pragma unroll
    for (int p = 0; p < 2; ++p) {
        const int g = 2*w + p;
        const float* PW = (g < 4) ? fpw : bpw;
        const float* row = PW + ((g & 3)*16 + ln)*67;
#pragma unroll
        for (int ks = 0; ks < 2; ++ks) {
            float tmp[8];
#pragma unroll
            for (int j = 0; j < 8; ++j) tmp[j] = row[3 + lq*8 + ks*32 + j];
            bpj[p][ks] = frag8(tmp);
        }
        {   // K-step 2: cols 64..66 = x0,x1,mc weights, rest 0
            float tmp[8];
#pragma unroll
            for (int j = 0; j < 8; ++j) tmp[j] = (lq == 0 && j < 3) ? row[j] : 0.f;
            bpj[p][2] = frag8(tmp);
        }
    }
    // fused-gate fragments: wave w -> dir = w>>1; z-mat and h-mat for that dir
    const int wdir = w >> 1, wmh = w & 1;
    short8 bgz[4][2], bgh[4][2];
    {
        const float* WZ = wdir ? bwz : fwz;
        const float* WH = wdir ? bwh : fwh;
#pragma unroll
        for (int nt = 0; nt < 4; ++nt) {
            const float* rz = WZ + (nt*16 + ln)*64;
            const float* rh = WH + (nt*16 + ln)*64;
#pragma unroll
            for (int ks = 0; ks < 2; ++ks) {
                bgz[nt][ks] = frag8(rz + lq*8 + ks*32);
                bgh[nt][ks] = frag8(rh + lq*8 + ks*32);
            }
        }
    }
    const float bias_te = te_b2[w*16 + ln];
    float bias_pj[2];
#pragma unroll
    for (int p = 0; p < 2; ++p) {
        const int g = 2*w + p;
        bias_pj[p] = ((g < 4) ? fpb : bpb)[(g & 3)*16 + ln];
    }
    float bias_gz[4], bias_gh[4];
    {
        const float* BZ = wdir ? bbz : fbz;
        const float* BH = wdir ? bbh : fbh;
#pragma unroll
        for (int nt = 0; nt < 4; ++nt) {
            bias_gz[nt] = BZ[nt*16 + ln];
            bias_gh[nt] = BH[nt*16 + ln];
        }
    }
    const float mt0 = mtok[0], mt1 = mtok[1];

    const int baseposl = blockIdx.x * 256;   // 4 chunks x 64

#pragma unroll 1
    for (int ch = 0; ch < 4; ++ch) {
        const int chbase = baseposl + ch*64;
        const int ll0   = chbase & 2047;
        const int bl    = chbase >> 11;
        const int gbase = (b0 << 11) + chbase;

        __syncthreads();   // protect u.p writes vs previous writer reads

        // ---- phase 0: stage te1 + xa (zero pad cols 4..39, data cols 0..3) ----
        {
            const int pos = tid & 63;
            const float tv = t[gbase + pos];
            const int k0 = (tid >> 6) * 16;                   // wave-uniform
            uint32_t* dst = (uint32_t*)(u.p.te1 + pos*72 + k0);
#pragma unroll
            for (int kk = 0; kk < 16; kk += 2) {
                float v0 = fmaxf(fmaf(tv, te_w1[k0+kk],   te_b1[k0+kk]),   0.f);
                float v1 = fmaxf(fmaf(tv, te_w1[k0+kk+1], te_b1[k0+kk+1]), 0.f);
                dst[kk >> 1] = pack2(v0, v1);
            }
            // zero pad: dwords 2..19 of each 20-dword row (no overlap with data dwords 0,1)
#pragma unroll
            for (int i = tid; i < 64*20; i += 256) {
                if ((i % 20) >= 2) ((uint32_t*)u.p.xa)[i] = 0;
            }
            if (tid < 64) {
                const float* xp = x + (size_t)(gbase + tid)*3;
                const float mc = xp[2];
                const float x0 = (mc == 0.f) ? mt0 : xp[0];
                const float x1 = (mc == 0.f) ? mt1 : xp[1];
                uint32_t* xr = (uint32_t*)(u.p.xa + tid*40);
                xr[0] = pack2(x0, x1);
                xr[1] = pack2(mc, 0.f);
            }
        }
        __syncthreads();

        // ---- GEMM1: tenc = te1 * te_w2^T + b ----
        {
            const int o = w*16 + ln;
#pragma unroll
            for (int mt = 0; mt < 4; ++mt) {
                f32x4 c = {0.f, 0.f, 0.f, 0.f};
#pragma unroll
                for (int ks = 0; ks < 2; ++ks) {
                    const short8 a = *(const short8*)(u.p.te1 + (mt*16+ln)*72 + lq*8 + ks*32);
                    c = MFMA16(a, bte[ks], c);
                }
#pragma unroll
                for (int r = 0; r < 4; ++r) {
                    const int m = mt*16 + lq*4 + r;
                    u.p.tenc[m*72 + o] = f2bf(c[r] + bias_te);
                }
            }
        }
        __syncthreads();

        // ---- GEMM2: inp_{f,b} = [tenc | x3pad] * pw'^T + pb ----
        {
#pragma unroll
            for (int mt = 0; mt < 4; ++mt) {
                short8 a0 = *(const short8*)(u.p.tenc + (mt*16+ln)*72 + lq*8);
                short8 a1 = *(const short8*)(u.p.tenc + (mt*16+ln)*72 + lq*8 + 32);
                short8 a2 = *(const short8*)(u.p.xa   + (mt*16+ln)*40 + lq*8);
#pragma unroll
                for (int p = 0; p < 2; ++p) {
                    const int g = 2*w + p;
                    const int dir = g >> 2;
                    const int o = (g & 3)*16 + ln;
                    f32x4 c = {0.f, 0.f, 0.f, 0.f};
                    c = MFMA16(a0, bpj[p][0], c);
                    c = MFMA16(a1, bpj[p][1], c);
                    c = MFMA16(a2, bpj[p][2], c);
#pragma unroll
                    for (int r = 0; r < 4; ++r) {
                        const int m = mt*16 + lq*4 + r;
                        s_inp[dir][m*72 + o] = f2bf(c[r] + bias_pj[p]);
                    }
                }
            }
        }
        __syncthreads();

        // ---- GEMM3 fused: wave (dir,mh) computes z AND h-tilde, packs (a,b) ----
        {
#pragma unroll
            for (int mt2 = 0; mt2 < 2; ++mt2) {
                const int mt = wmh*2 + mt2;
                const short8 a0 = *(const short8*)(s_inp[wdir] + (mt*16+ln)*72 + lq*8);
                const short8 a1 = *(const short8*)(s_inp[wdir] + (mt*16+ln)*72 + lq*8 + 32);
#pragma unroll
                for (int nt = 0; nt < 4; ++nt) {
                    f32x4 cz = {0.f, 0.f, 0.f, 0.f};
                    f32x4 ch2 = {0.f, 0.f, 0.f, 0.f};
                    cz  = MFMA16(a0, bgz[nt][0], cz);
                    cz  = MFMA16(a1, bgz[nt][1], cz);
                    ch2 = MFMA16(a0, bgh[nt][0], ch2);
                    ch2 = MFMA16(a1, bgh[nt][1], ch2);
                    const int o = nt*16 + ln;
#pragma unroll
                    for (int r = 0; r < 4; ++r) {
                        const int m = mt*16 + lq*4 + r;
                        const float az = cz[r]  + bias_gz[nt];
                        const float ah = ch2[r] + bias_gh[nt];
                        const float z  = 1.f / (1.f + __expf(-az));
                        const float cc = fminf(fmaxf(ah, -15.f), 15.f);
                        const float e  = __expf(2.f * cc);
                        const float th = (e - 1.f) / (e + 1.f);
                        u.ab[wdir][m*65 + o] = pack2(1.f - z, z * th);
                    }
                }
            }
        }
        __syncthreads();

        // ---- writer: pure LDS->global transpose, coalesced 256 B stores ----
        {
#pragma unroll 1
            for (int d = 0; d < 2; ++d) {
                uint32_t* dst = (d ? abb : abf) + (size_t)(bl*64)*NL + ll0;
                const uint32_t* src = u.ab[d];
#pragma unroll
                for (int rep = 0; rep < 16; ++rep) {
                    const int idx = rep*256 + tid;
                    const int o = idx >> 6, row = idx & 63;
                    dst[(size_t)o*NL + row] = src[row*65 + o];
                }
            }
        }
    }
}

// ---------- kernel 2: 2*Bg*64 independent linear scans (unchanged) ----------
__global__ __launch_bounds__(64) void scan_kernel(
    const uint32_t* __restrict__ abf, const uint32_t* __restrict__ abb,
    int Bg,
    unsigned short* __restrict__ hf, unsigned short* __restrict__ hb) // [b_l][l][h] bf16
{
    const int tid = blockIdx.x * 64 + threadIdx.x;
    const int nfw = Bg * 64;
    const int dir = (tid >= nfw) ? 1 : 0;
    const int bh  = tid - dir * nfw;
    const int bl  = bh >> 6;
    const int hh  = bh & 63;

    const uint32_t* ab = (dir ? abb : abf) + (size_t)bh * NL;
    unsigned short* out = (dir ? hb : hf) + (size_t)bl * NL * 64 + hh;

    float hv = 0.f;
    if (dir == 0) {
#pragma unroll 1
        for (int l0 = 0; l0 < NL; l0 += 32) {
            const uint4* p = (const uint4*)(ab + l0);
            uint4 v[8];
#pragma unroll
            for (int i = 0; i < 8; ++i) v[i] = p[i];
            uint32_t q[32];
#pragma unroll
            for (int i = 0; i < 8; ++i) {
                q[4*i+0]=v[i].x; q[4*i+1]=v[i].y; q[4*i+2]=v[i].z; q[4*i+3]=v[i].w;
            }
            unsigned short* op = out + (size_t)l0 * 64;
#pragma unroll
            for (int i = 0; i < 32; ++i) {
                *op = f2bf(hv); op += 64;
                hv = fmaf(bflo(q[i]), hv, bfhi(q[i]));
            }
        }
    } else {
#pragma unroll 1
        for (int l0 = NL - 32; l0 >= 0; l0 -= 32) {
            const uint4* p = (const uint4*)(ab + l0);
            uint4 v[8];
#pragma unroll
            for (int i = 0; i < 8; ++i) v[i] = p[i];
            uint32_t q[32];
#pragma unroll
            for (int i = 0; i < 8; ++i) {
                q[4*i+0]=v[i].x; q[4*i+1]=v[i].y; q[4*i+2]=v[i].z; q[4*i+3]=v[i].w;
            }
            unsigned short* op = out + (size_t)(l0 + 31) * 64;
#pragma unroll
            for (int i = 31; i >= 0; --i) {
                *op = f2bf(hv); op -= 64;
                hv = fmaf(bflo(q[i]), hv, bfhi(q[i]));
            }
        }
    }
}

// =====================================================================
// kernel 3: MFMA head — recompute tenc, [hf|hb|tenc](192) -> 128 relu -> 1
// block = 256 thr, 4 chunks of 64 positions; grid = 8*Bg
// =====================================================================
union HeadU {
    unsigned short te1[64*72];   //  9216 B
    float hid[64*133];           // 34048 B
};

__global__ __launch_bounds__(256, 2) void head_kernel(
    const float* __restrict__ x, const float* __restrict__ t,
    const float* __restrict__ te_w1, const float* __restrict__ te_b1,
    const float* __restrict__ te_w2, const float* __restrict__ te_b2,
    const unsigned short* __restrict__ hf, const unsigned short* __restrict__ hb,
    const float* __restrict__ w1, const float* __restrict__ b1,  // [128,192],[128]
    const float* __restrict__ w2, const float* __restrict__ b2,  // [1,128],[1]
    int b0,
    float* __restrict__ out)
{
    __shared__ __align__(16) unsigned short s_a[64*200];   // 25600 B
    __shared__ __align__(16) HeadU hu;                     // 34048 B
    __shared__ float s_pac[256];

    const int tid = threadIdx.x;
    const int w   = tid >> 6;
    const int l   = tid & 63;
    const int lq  = l >> 4;
    const int ln  = l & 15;

    // ---- W1 fragments + per-lane b1/w2 + te_w2 fragments ----
    short8 bw1[2][6];
    float b1v[2], w2v[2];
#pragma unroll
    for (int p = 0; p < 2; ++p) {
        const int o = (2*w + p)*16 + ln;
        const float* row = w1 + o*192;
#pragma unroll
        for (int ks = 0; ks < 6; ++ks) bw1[p][ks] = frag8(row + lq*8 + ks*32);
        b1v[p] = b1[o];
        w2v[p] = w2[o];
    }
    short8 bte[2];
    {
        const float* row = te_w2 + (w*16 + ln)*64;
#pragma unroll
        for (int ks = 0; ks < 2; ++ks) bte[ks] = frag8(row + lq*8 + ks*32);
    }
    const float bias_te = te_b2[w*16 + ln];
    const float bias2 = b2[0];

    const int baseposl = blockIdx.x * 256;

#pragma unroll 1
    for (int ch = 0; ch < 4; ++ch) {
        const int chbase = baseposl + ch*64;
        const int ll0   = chbase & 2047;
        const int bl    = chbase >> 11;
        const int gbase = (b0 << 11) + chbase;
        const size_t rowbase = (size_t)bl * NL * 64;

        // ---- stage: hf/hb tiles into s_a cols 0..127, te1 into hu.te1 ----
        {
#pragma unroll 1
            for (int seg = 0; seg < 2; ++seg) {
#pragma unroll
                for (int rep = 0; rep < 8; ++rep) {
                    const int idx = rep*256 + tid;
                    const int row = idx >> 5, c = idx & 31;
                    const float mc = x[(size_t)(gbase + row)*3 + 2];
                    const bool unm = mc > 0.f;
                    const uint32_t* src = (seg == 0)
                        ? (const uint32_t*)(hf + rowbase + (size_t)(unm ? (ll0+row) : (NL-1))*64)
                        : (const uint32_t*)(hb + rowbase + (size_t)(unm ? (ll0+row) : 0)*64);
                    ((uint32_t*)s_a)[row*100 + seg*32 + c] = src[c];
                }
            }
            const int pos = tid & 63;
            const float tv = t[gbase + pos];
            const int k0 = (tid >> 6) * 16;
            uint32_t* dst = (uint32_t*)(hu.te1 + pos*72 + k0);
#pragma unroll
            for (int kk = 0; kk < 16; kk += 2) {
                float v0 = fmaxf(fmaf(tv, te_w1[k0+kk],   te_b1[k0+kk]),   0.f);
                float v1 = fmaxf(fmaf(tv, te_w1[k0+kk+1], te_b1[k0+kk+1]), 0.f);
                dst[kk >> 1] = pack2(v0, v1);
            }
        }
        __syncthreads();

        // ---- tenc GEMM: s_a cols 128..191 = f2bf(te1 * te_w2^T + b) ----
        {
            const int o = w*16 + ln;
#pragma unroll
            for (int mt = 0; mt < 4; ++mt) {
                f32x4 c = {0.f, 0.f, 0.f, 0.f};
#pragma unroll
                for (int ks = 0; ks < 2; ++ks) {
                    const short8 a = *(const short8*)(hu.te1 + (mt*16+ln)*72 + lq*8 + ks*32);
                    c = MFMA16(a, bte[ks], c);
                }
#pragma unroll
                for (int r = 0; r < 4; ++r) {
                    const int m = mt*16 + lq*4 + r;
                    s_a[m*200 + 128 + o] = f2bf(c[r] + bias_te);
                }
            }
        }
        __syncthreads();

        // ---- GEMM1 + premultiplied-hid epilogue (clobbers hu.te1 via union) ----
        {
#pragma unroll
            for (int mt = 0; mt < 4; ++mt) {
                short8 af[6];
#pragma unroll
                for (int ks = 0; ks < 6; ++ks)
                    af[ks] = *(const short8*)(s_a + (mt*16+ln)*200 + lq*8 + ks*32);
#pragma unroll
                for (int p = 0; p < 2; ++p) {
                    f32x4 c = {0.f, 0.f, 0.f, 0.f};
#pragma unroll
                    for (int ks = 0; ks < 6; ++ks) c = MFMA16(af[ks], bw1[p][ks], c);
                    const int o = (2*w + p)*16 + ln;
#pragma unroll
                    for (int r = 0; r < 4; ++r) {
                        const int m = mt*16 + lq*4 + r;
                        hu.hid[m*133 + o] = fmaxf(c[r] + b1v[p], 0.f) * w2v[p];
                    }
                }
            }
        }
        __syncthreads();

        // ---- GEMM2: row sums (4 threads per row, rotated) ----
        {
            const int m = tid >> 2, part = tid & 3;
            const float* hrow = hu.hid + m*133;
            float s = 0.f;
#pragma unroll
            for (int i = 0; i < 32; ++i) {
                const int c = part*32 + ((i + part*8) & 31);
                s += hrow[c];
            }
            s_pac[tid] = s;
        }
        __syncthreads();
        if (tid < 64) {
            out[gbase + tid] = s_pac[tid*4] + s_pac[tid*4+1] + s_pac[tid*4+2] + s_pac[tid*4+3] + bias2;
        }
        __syncthreads();
    }
}

extern "C" void kernel_launch(void* const* d_in, const int* in_sizes, int n_in,
                              void* d_out, int out_size, void* d_ws, size_t ws_size,
                              hipStream_t stream)
{
    const float* x     = (const float*)d_in[0];
    const float* t     = (const float*)d_in[1];
    const float* mtok  = (const float*)d_in[2];
    const float* te_w1 = (const float*)d_in[3];
    const float* te_b1 = (const float*)d_in[4];
    const float* te_w2 = (const float*)d_in[5];
    const float* te_b2 = (const float*)d_in[6];
    const float* fpw   = (const float*)d_in[7];
    const float* fpb   = (const float*)d_in[8];
    const float* bpw   = (const float*)d_in[9];
    const float* bpb   = (const float*)d_in[10];
    const float* fwz   = (const float*)d_in[11];
    const float* fbz   = (const float*)d_in[12];
    const float* fwh   = (const float*)d_in[13];
    const float* fbh   = (const float*)d_in[14];
    const float* bwz   = (const float*)d_in[15];
    const float* bbz   = (const float*)d_in[16];
    const float* bwh   = (const float*)d_in[17];
    const float* bbh   = (const float*)d_in[18];
    const float* w1    = (const float*)d_in[19];
    const float* b1    = (const float*)d_in[20];
    const float* w2    = (const float*)d_in[21];
    const float* b2    = (const float*)d_in[22];

    // Per-batch-row workspace footprint (bytes):
    //   abf+abb : 2 * 64*2048*4 = 1,048,576
    //   hf+hb   : 2 * 2048*64*2 =   524,288
    const size_t per_b = 1572864ull;
    int Bg = NB;
    while ((size_t)Bg * per_b > ws_size && Bg > 1) Bg >>= 1;
    const int nG = NB / Bg;

    char* ws = (char*)d_ws;
    uint32_t*       abf  = (uint32_t*)(ws);
    uint32_t*       abb  = abf + (size_t)Bg * 64 * NL;
    unsigned short* hf   = (unsigned short*)(abb + (size_t)Bg * 64 * NL);
    unsigned short* hb   = hf + (size_t)Bg * NL * 64;

    for (int g = 0; g < nG; ++g) {
        const int b0 = g * Bg;

        prep_kernel<<<8 * Bg, 256, 0, stream>>>(
            x, t, mtok, te_w1, te_b1, te_w2, te_b2,
            fpw, fpb, bpw, bpb, fwz, fbz, fwh, fbh, bwz, bbz, bwh, bbh,
            b0, abf, abb);

        scan_kernel<<<2 * Bg, 64, 0, stream>>>(abf, abb, Bg, hf, hb);

        head_kernel<<<8 * Bg, 256, 0, stream>>>(
            x, t, te_w1, te_b1, te_w2, te_b2,
            hf, hb, w1, b1, w2, b2, b0, (float*)d_out);
    }
}

// Round 6
// 479.214 us; speedup vs baseline: 1.5160x; 1.5160x over previous
//
#include <hip/hip_runtime.h>
#include <stdint.h>

// Problem constants (B=256, L=2048, H=64, TE=64)
#define NB 256
#define NL 2048

typedef __attribute__((ext_vector_type(8))) short short8;
typedef __attribute__((ext_vector_type(4))) float f32x4;
#define MFMA16(a,b,c) __builtin_amdgcn_mfma_f32_16x16x32_bf16(a,b,c,0,0,0)

// ---------- bf16 helpers (manual, RNE) ----------
static __device__ __forceinline__ unsigned short f2bf(float f) {
    union { float f; uint32_t u; } v; v.f = f;
    uint32_t u = v.u;
    uint32_t r = u + 0x7fffu + ((u >> 16) & 1u);
    return (unsigned short)(r >> 16);
}
static __device__ __forceinline__ float bflo(uint32_t u) {
    union { uint32_t u; float f; } v; v.u = u << 16; return v.f;
}
static __device__ __forceinline__ float bfhi(uint32_t u) {
    union { uint32_t u; float f; } v; v.u = u & 0xffff0000u; return v.f;
}
static __device__ __forceinline__ uint32_t pack2(float lo, float hi) {
    return ((uint32_t)f2bf(hi) << 16) | (uint32_t)f2bf(lo);
}
static __device__ __forceinline__ short8 frag8(const float* p) {
    short8 r;
#pragma unroll
    for (int j = 0; j < 8; ++j) r[j] = (short)f2bf(p[j]);
    return r;
}

// =====================================================================
// kernel 1: MFMA prep — time-MLP + proj + gates -> packed (a,b)
// block = 256 thr (4 waves), 4 chunks of 64 positions; grid = 8*Bg
// GEMM3 split by nt-pair (not m) to halve gate-fragment VGPRs (spill fix, R5)
// =====================================================================
union PrepU {
    struct {
        unsigned short te1[64*72];    //  9216 B
        unsigned short tenc[64*72];   //  9216 B
        unsigned short xa[64*40];     //  5120 B
    } p;
    uint32_t ab[2][64*65];            // 33280 B (packed a|b, stride 65)
};

__global__ __launch_bounds__(256, 3) void prep_kernel(
    const float* __restrict__ x, const float* __restrict__ t,
    const float* __restrict__ mtok,
    const float* __restrict__ te_w1, const float* __restrict__ te_b1,
    const float* __restrict__ te_w2, const float* __restrict__ te_b2,
    const float* __restrict__ fpw, const float* __restrict__ fpb,
    const float* __restrict__ bpw, const float* __restrict__ bpb,
    const float* __restrict__ fwz, const float* __restrict__ fbz,
    const float* __restrict__ fwh, const float* __restrict__ fbh,
    const float* __restrict__ bwz, const float* __restrict__ bbz,
    const float* __restrict__ bwh, const float* __restrict__ bbh,
    int b0,
    uint32_t* __restrict__ abf,              // [Bg*64, L] packed (a lo, b hi)
    uint32_t* __restrict__ abb)
{
    __shared__ __align__(16) PrepU u;
    __shared__ __align__(16) unsigned short s_inp[2][64*72];  // 18432 B

    const int tid = threadIdx.x;
    const int w   = tid >> 6;     // wave 0..3
    const int l   = tid & 63;
    const int lq  = l >> 4;       // quad
    const int ln  = l & 15;

    // ---- weight B-fragments (once per block) ----
    short8 bte[2];
    {
        const float* row = te_w2 + (w*16 + ln)*64;
#pragma unroll
        for (int ks = 0; ks < 2; ++ks) bte[ks] = frag8(row + lq*8 + ks*32);
    }
    short8 bpj[2][3];
#pragma unroll
    for (int p = 0; p < 2; ++p) {
        const int g = 2*w + p;
        const float* PW = (g < 4) ? fpw : bpw;
        const float* row = PW + ((g & 3)*16 + ln)*67;
#pragma unroll
        for (int ks = 0; ks < 2; ++ks) {
            float tmp[8];
#pragma unroll
            for (int j = 0; j < 8; ++j) tmp[j] = row[3 + lq*8 + ks*32 + j];
            bpj[p][ks] = frag8(tmp);
        }
        {   // K-step 2: cols 64..66 = x0,x1,mc weights, rest 0
            float tmp[8];
#pragma unroll
            for (int j = 0; j < 8; ++j) tmp[j] = (lq == 0 && j < 3) ? row[j] : 0.f;
            bpj[p][2] = frag8(tmp);
        }
    }
    // gate fragments: wave w -> dir = w>>1, nt-pair = w&1 (both z and h mats)
    const int wdir = w >> 1, wnp = w & 1;
    short8 bgz[2][2], bgh[2][2];
    float bias_gz[2], bias_gh[2];
    {
        const float* WZ = wdir ? bwz : fwz;
        const float* WH = wdir ? bwh : fwh;
        const float* BZ = wdir ? bbz : fbz;
        const float* BH = wdir ? bbh : fbh;
#pragma unroll
        for (int nt2 = 0; nt2 < 2; ++nt2) {
            const int nt = wnp*2 + nt2;
            const float* rz = WZ + (nt*16 + ln)*64;
            const float* rh = WH + (nt*16 + ln)*64;
#pragma unroll
            for (int ks = 0; ks < 2; ++ks) {
                bgz[nt2][ks] = frag8(rz + lq*8 + ks*32);
                bgh[nt2][ks] = frag8(rh + lq*8 + ks*32);
            }
            bias_gz[nt2] = BZ[nt*16 + ln];
            bias_gh[nt2] = BH[nt*16 + ln];
        }
    }
    const float bias_te = te_b2[w*16 + ln];
    float bias_pj[2];
#pragma unroll
    for (int p = 0; p < 2; ++p) {
        const int g = 2*w + p;
        bias_pj[p] = ((g < 4) ? fpb : bpb)[(g & 3)*16 + ln];
    }
    const float mt0 = mtok[0], mt1 = mtok[1];

    const int baseposl = blockIdx.x * 256;   // 4 chunks x 64

#pragma unroll 1
    for (int ch = 0; ch < 4; ++ch) {
        const int chbase = baseposl + ch*64;
        const int ll0   = chbase & 2047;
        const int bl    = chbase >> 11;
        const int gbase = (b0 << 11) + chbase;

        __syncthreads();   // protect u.p writes vs previous writer reads

        // ---- phase 0: stage te1 + xa (zero pad dwords 2..19, data dwords 0..1) ----
        {
            const int pos = tid & 63;
            const float tv = t[gbase + pos];
            const int k0 = (tid >> 6) * 16;                   // wave-uniform
            uint32_t* dst = (uint32_t*)(u.p.te1 + pos*72 + k0);
#pragma unroll
            for (int kk = 0; kk < 16; kk += 2) {
                float v0 = fmaxf(fmaf(tv, te_w1[k0+kk],   te_b1[k0+kk]),   0.f);
                float v1 = fmaxf(fmaf(tv, te_w1[k0+kk+1], te_b1[k0+kk+1]), 0.f);
                dst[kk >> 1] = pack2(v0, v1);
            }
#pragma unroll
            for (int i = tid; i < 64*20; i += 256) {
                if ((i % 20) >= 2) ((uint32_t*)u.p.xa)[i] = 0;
            }
            if (tid < 64) {
                const float* xp = x + (size_t)(gbase + tid)*3;
                const float mc = xp[2];
                const float x0 = (mc == 0.f) ? mt0 : xp[0];
                const float x1 = (mc == 0.f) ? mt1 : xp[1];
                uint32_t* xr = (uint32_t*)(u.p.xa + tid*40);
                xr[0] = pack2(x0, x1);
                xr[1] = pack2(mc, 0.f);
            }
        }
        __syncthreads();

        // ---- GEMM1: tenc = te1 * te_w2^T + b ----
        {
            const int o = w*16 + ln;
#pragma unroll
            for (int mt = 0; mt < 4; ++mt) {
                f32x4 c = {0.f, 0.f, 0.f, 0.f};
#pragma unroll
                for (int ks = 0; ks < 2; ++ks) {
                    const short8 a = *(const short8*)(u.p.te1 + (mt*16+ln)*72 + lq*8 + ks*32);
                    c = MFMA16(a, bte[ks], c);
                }
#pragma unroll
                for (int r = 0; r < 4; ++r) {
                    const int m = mt*16 + lq*4 + r;
                    u.p.tenc[m*72 + o] = f2bf(c[r] + bias_te);
                }
            }
        }
        __syncthreads();

        // ---- GEMM2: inp_{f,b} = [tenc | x3pad] * pw'^T + pb ----
        {
#pragma unroll
            for (int mt = 0; mt < 4; ++mt) {
                short8 a0 = *(const short8*)(u.p.tenc + (mt*16+ln)*72 + lq*8);
                short8 a1 = *(const short8*)(u.p.tenc + (mt*16+ln)*72 + lq*8 + 32);
                short8 a2 = *(const short8*)(u.p.xa   + (mt*16+ln)*40 + lq*8);
#pragma unroll
                for (int p = 0; p < 2; ++p) {
                    const int g = 2*w + p;
                    const int dir = g >> 2;
                    const int o = (g & 3)*16 + ln;
                    f32x4 c = {0.f, 0.f, 0.f, 0.f};
                    c = MFMA16(a0, bpj[p][0], c);
                    c = MFMA16(a1, bpj[p][1], c);
                    c = MFMA16(a2, bpj[p][2], c);
#pragma unroll
                    for (int r = 0; r < 4; ++r) {
                        const int m = mt*16 + lq*4 + r;
                        s_inp[dir][m*72 + o] = f2bf(c[r] + bias_pj[p]);
                    }
                }
            }
        }
        __syncthreads();

        // ---- GEMM3 fused: wave (dir, nt-pair) computes z AND h-tilde, packs (a,b) ----
        {
#pragma unroll
            for (int mt = 0; mt < 4; ++mt) {
                const short8 a0 = *(const short8*)(s_inp[wdir] + (mt*16+ln)*72 + lq*8);
                const short8 a1 = *(const short8*)(s_inp[wdir] + (mt*16+ln)*72 + lq*8 + 32);
#pragma unroll
                for (int nt2 = 0; nt2 < 2; ++nt2) {
                    f32x4 cz = {0.f, 0.f, 0.f, 0.f};
                    f32x4 ch2 = {0.f, 0.f, 0.f, 0.f};
                    cz  = MFMA16(a0, bgz[nt2][0], cz);
                    cz  = MFMA16(a1, bgz[nt2][1], cz);
                    ch2 = MFMA16(a0, bgh[nt2][0], ch2);
                    ch2 = MFMA16(a1, bgh[nt2][1], ch2);
                    const int o = (wnp*2 + nt2)*16 + ln;
#pragma unroll
                    for (int r = 0; r < 4; ++r) {
                        const int m = mt*16 + lq*4 + r;
                        const float az = cz[r]  + bias_gz[nt2];
                        const float ah = ch2[r] + bias_gh[nt2];
                        const float z  = 1.f / (1.f + __expf(-az));
                        const float cc = fminf(fmaxf(ah, -15.f), 15.f);
                        const float e  = __expf(2.f * cc);
                        const float th = (e - 1.f) / (e + 1.f);
                        u.ab[wdir][m*65 + o] = pack2(1.f - z, z * th);
                    }
                }
            }
        }
        __syncthreads();

        // ---- writer: pure LDS->global transpose, coalesced 256 B stores ----
        {
#pragma unroll 1
            for (int d = 0; d < 2; ++d) {
                uint32_t* dst = (d ? abb : abf) + (size_t)(bl*64)*NL + ll0;
                const uint32_t* src = u.ab[d];
#pragma unroll
                for (int rep = 0; rep < 16; ++rep) {
                    const int idx = rep*256 + tid;
                    const int o = idx >> 6, row = idx & 63;
                    dst[(size_t)o*NL + row] = src[row*65 + o];
                }
            }
        }
    }
}

// ---------- kernel 2: 2*Bg*64 independent linear scans (unchanged) ----------
__global__ __launch_bounds__(64) void scan_kernel(
    const uint32_t* __restrict__ abf, const uint32_t* __restrict__ abb,
    int Bg,
    unsigned short* __restrict__ hf, unsigned short* __restrict__ hb) // [b_l][l][h] bf16
{
    const int tid = blockIdx.x * 64 + threadIdx.x;
    const int nfw = Bg * 64;
    const int dir = (tid >= nfw) ? 1 : 0;
    const int bh  = tid - dir * nfw;
    const int bl  = bh >> 6;
    const int hh  = bh & 63;

    const uint32_t* ab = (dir ? abb : abf) + (size_t)bh * NL;
    unsigned short* out = (dir ? hb : hf) + (size_t)bl * NL * 64 + hh;

    float hv = 0.f;
    if (dir == 0) {
#pragma unroll 1
        for (int l0 = 0; l0 < NL; l0 += 32) {
            const uint4* p = (const uint4*)(ab + l0);
            uint4 v[8];
#pragma unroll
            for (int i = 0; i < 8; ++i) v[i] = p[i];
            uint32_t q[32];
#pragma unroll
            for (int i = 0; i < 8; ++i) {
                q[4*i+0]=v[i].x; q[4*i+1]=v[i].y; q[4*i+2]=v[i].z; q[4*i+3]=v[i].w;
            }
            unsigned short* op = out + (size_t)l0 * 64;
#pragma unroll
            for (int i = 0; i < 32; ++i) {
                *op = f2bf(hv); op += 64;
                hv = fmaf(bflo(q[i]), hv, bfhi(q[i]));
            }
        }
    } else {
#pragma unroll 1
        for (int l0 = NL - 32; l0 >= 0; l0 -= 32) {
            const uint4* p = (const uint4*)(ab + l0);
            uint4 v[8];
#pragma unroll
            for (int i = 0; i < 8; ++i) v[i] = p[i];
            uint32_t q[32];
#pragma unroll
            for (int i = 0; i < 8; ++i) {
                q[4*i+0]=v[i].x; q[4*i+1]=v[i].y; q[4*i+2]=v[i].z; q[4*i+3]=v[i].w;
            }
            unsigned short* op = out + (size_t)(l0 + 31) * 64;
#pragma unroll
            for (int i = 31; i >= 0; --i) {
                *op = f2bf(hv); op -= 64;
                hv = fmaf(bflo(q[i]), hv, bfhi(q[i]));
            }
        }
    }
}

// =====================================================================
// kernel 3: MFMA head — recompute tenc, [hf|hb|tenc](192) -> 128 relu -> 1
// block = 256 thr, 4 chunks of 64 positions; grid = 8*Bg
// =====================================================================
union HeadU {
    unsigned short te1[64*72];   //  9216 B
    float hid[64*133];           // 34048 B
};

__global__ __launch_bounds__(256, 2) void head_kernel(
    const float* __restrict__ x, const float* __restrict__ t,
    const float* __restrict__ te_w1, const float* __restrict__ te_b1,
    const float* __restrict__ te_w2, const float* __restrict__ te_b2,
    const unsigned short* __restrict__ hf, const unsigned short* __restrict__ hb,
    const float* __restrict__ w1, const float* __restrict__ b1,  // [128,192],[128]
    const float* __restrict__ w2, const float* __restrict__ b2,  // [1,128],[1]
    int b0,
    float* __restrict__ out)
{
    __shared__ __align__(16) unsigned short s_a[64*200];   // 25600 B
    __shared__ __align__(16) HeadU hu;                     // 34048 B
    __shared__ float s_pac[256];

    const int tid = threadIdx.x;
    const int w   = tid >> 6;
    const int l   = tid & 63;
    const int lq  = l >> 4;
    const int ln  = l & 15;

    // ---- W1 fragments + per-lane b1/w2 + te_w2 fragments ----
    short8 bw1[2][6];
    float b1v[2], w2v[2];
#pragma unroll
    for (int p = 0; p < 2; ++p) {
        const int o = (2*w + p)*16 + ln;
        const float* row = w1 + o*192;
#pragma unroll
        for (int ks = 0; ks < 6; ++ks) bw1[p][ks] = frag8(row + lq*8 + ks*32);
        b1v[p] = b1[o];
        w2v[p] = w2[o];
    }
    short8 bte[2];
    {
        const float* row = te_w2 + (w*16 + ln)*64;
#pragma unroll
        for (int ks = 0; ks < 2; ++ks) bte[ks] = frag8(row + lq*8 + ks*32);
    }
    const float bias_te = te_b2[w*16 + ln];
    const float bias2 = b2[0];

    const int baseposl = blockIdx.x * 256;

#pragma unroll 1
    for (int ch = 0; ch < 4; ++ch) {
        const int chbase = baseposl + ch*64;
        const int ll0   = chbase & 2047;
        const int bl    = chbase >> 11;
        const int gbase = (b0 << 11) + chbase;
        const size_t rowbase = (size_t)bl * NL * 64;

        // ---- stage: hf/hb tiles into s_a cols 0..127, te1 into hu.te1 ----
        {
#pragma unroll 1
            for (int seg = 0; seg < 2; ++seg) {
#pragma unroll
                for (int rep = 0; rep < 8; ++rep) {
                    const int idx = rep*256 + tid;
                    const int row = idx >> 5, c = idx & 31;
                    const float mc = x[(size_t)(gbase + row)*3 + 2];
                    const bool unm = mc > 0.f;
                    const uint32_t* src = (seg == 0)
                        ? (const uint32_t*)(hf + rowbase + (size_t)(unm ? (ll0+row) : (NL-1))*64)
                        : (const uint32_t*)(hb + rowbase + (size_t)(unm ? (ll0+row) : 0)*64);
                    ((uint32_t*)s_a)[row*100 + seg*32 + c] = src[c];
                }
            }
            const int pos = tid & 63;
            const float tv = t[gbase + pos];
            const int k0 = (tid >> 6) * 16;
            uint32_t* dst = (uint32_t*)(hu.te1 + pos*72 + k0);
#pragma unroll
            for (int kk = 0; kk < 16; kk += 2) {
                float v0 = fmaxf(fmaf(tv, te_w1[k0+kk],   te_b1[k0+kk]),   0.f);
                float v1 = fmaxf(fmaf(tv, te_w1[k0+kk+1], te_b1[k0+kk+1]), 0.f);
                dst[kk >> 1] = pack2(v0, v1);
            }
        }
        __syncthreads();

        // ---- tenc GEMM: s_a cols 128..191 = f2bf(te1 * te_w2^T + b) ----
        {
            const int o = w*16 + ln;
#pragma unroll
            for (int mt = 0; mt < 4; ++mt) {
                f32x4 c = {0.f, 0.f, 0.f, 0.f};
#pragma unroll
                for (int ks = 0; ks < 2; ++ks) {
                    const short8 a = *(const short8*)(hu.te1 + (mt*16+ln)*72 + lq*8 + ks*32);
                    c = MFMA16(a, bte[ks], c);
                }
#pragma unroll
                for (int r = 0; r < 4; ++r) {
                    const int m = mt*16 + lq*4 + r;
                    s_a[m*200 + 128 + o] = f2bf(c[r] + bias_te);
                }
            }
        }
        __syncthreads();

        // ---- GEMM1 + premultiplied-hid epilogue (clobbers hu.te1 via union) ----
        {
#pragma unroll
            for (int mt = 0; mt < 4; ++mt) {
                short8 af[6];
#pragma unroll
                for (int ks = 0; ks < 6; ++ks)
                    af[ks] = *(const short8*)(s_a + (mt*16+ln)*200 + lq*8 + ks*32);
#pragma unroll
                for (int p = 0; p < 2; ++p) {
                    f32x4 c = {0.f, 0.f, 0.f, 0.f};
#pragma unroll
                    for (int ks = 0; ks < 6; ++ks) c = MFMA16(af[ks], bw1[p][ks], c);
                    const int o = (2*w + p)*16 + ln;
#pragma unroll
                    for (int r = 0; r < 4; ++r) {
                        const int m = mt*16 + lq*4 + r;
                        hu.hid[m*133 + o] = fmaxf(c[r] + b1v[p], 0.f) * w2v[p];
                    }
                }
            }
        }
        __syncthreads();

        // ---- GEMM2: row sums (4 threads per row, rotated) ----
        {
            const int m = tid >> 2, part = tid & 3;
            const float* hrow = hu.hid + m*133;
            float s = 0.f;
#pragma unroll
            for (int i = 0; i < 32; ++i) {
                const int c = part*32 + ((i + part*8) & 31);
                s += hrow[c];
            }
            s_pac[tid] = s;
        }
        __syncthreads();
        if (tid < 64) {
            out[gbase + tid] = s_pac[tid*4] + s_pac[tid*4+1] + s_pac[tid*4+2] + s_pac[tid*4+3] + bias2;
        }
        __syncthreads();
    }
}

extern "C" void kernel_launch(void* const* d_in, const int* in_sizes, int n_in,
                              void* d_out, int out_size, void* d_ws, size_t ws_size,
                              hipStream_t stream)
{
    const float* x     = (const float*)d_in[0];
    const float* t     = (const float*)d_in[1];
    const float* mtok  = (const float*)d_in[2];
    const float* te_w1 = (const float*)d_in[3];
    const float* te_b1 = (const float*)d_in[4];
    const float* te_w2 = (const float*)d_in[5];
    const float* te_b2 = (const float*)d_in[6];
    const float* fpw   = (const float*)d_in[7];
    const float* fpb   = (const float*)d_in[8];
    const float* bpw   = (const float*)d_in[9];
    const float* bpb   = (const float*)d_in[10];
    const float* fwz   = (const float*)d_in[11];
    const float* fbz   = (const float*)d_in[12];
    const float* fwh   = (const float*)d_in[13];
    const float* fbh   = (const float*)d_in[14];
    const float* bwz   = (const float*)d_in[15];
    const float* bbz   = (const float*)d_in[16];
    const float* bwh   = (const float*)d_in[17];
    const float* bbh   = (const float*)d_in[18];
    const float* w1    = (const float*)d_in[19];
    const float* b1    = (const float*)d_in[20];
    const float* w2    = (const float*)d_in[21];
    const float* b2    = (const float*)d_in[22];

    // Per-batch-row workspace footprint (bytes):
    //   abf+abb : 2 * 64*2048*4 = 1,048,576
    //   hf+hb   : 2 * 2048*64*2 =   524,288
    const size_t per_b = 1572864ull;
    int Bg = NB;
    while ((size_t)Bg * per_b > ws_size && Bg > 1) Bg >>= 1;
    const int nG = NB / Bg;

    char* ws = (char*)d_ws;
    uint32_t*       abf  = (uint32_t*)(ws);
    uint32_t*       abb  = abf + (size_t)Bg * 64 * NL;
    unsigned short* hf   = (unsigned short*)(abb + (size_t)Bg * 64 * NL);
    unsigned short* hb   = hf + (size_t)Bg * NL * 64;

    for (int g = 0; g < nG; ++g) {
        const int b0 = g * Bg;

        prep_kernel<<<8 * Bg, 256, 0, stream>>>(
            x, t, mtok, te_w1, te_b1, te_w2, te_b2,
            fpw, fpb, bpw, bpb, fwz, fbz, fwh, fbh, bwz, bbz, bwh, bbh,
            b0, abf, abb);

        scan_kernel<<<2 * Bg, 64, 0, stream>>>(abf, abb, Bg, hf, hb);

        head_kernel<<<8 * Bg, 256, 0, stream>>>(
            x, t, te_w1, te_b1, te_w2, te_b2,
            hf, hb, w1, b1, w2, b2, b0, (float*)d_out);
    }
}

// Round 8
// 476.116 us; speedup vs baseline: 1.5258x; 1.0065x over previous
//
#include <hip/hip_runtime.h>
#include <stdint.h>

// Problem constants (B=256, L=2048, H=64, TE=64)
#define NB 256
#define NL 2048

typedef __attribute__((ext_vector_type(8))) short short8;
typedef __attribute__((ext_vector_type(4))) float f32x4;
#define MFMA16(a,b,c) __builtin_amdgcn_mfma_f32_16x16x32_bf16(a,b,c,0,0,0)

// ---------- bf16 helpers (manual, RNE) ----------
static __device__ __forceinline__ unsigned short f2bf(float f) {
    union { float f; uint32_t u; } v; v.f = f;
    uint32_t u = v.u;
    uint32_t r = u + 0x7fffu + ((u >> 16) & 1u);
    return (unsigned short)(r >> 16);
}
static __device__ __forceinline__ float bflo(uint32_t u) {
    union { uint32_t u; float f; } v; v.u = u << 16; return v.f;
}
static __device__ __forceinline__ float bfhi(uint32_t u) {
    union { uint32_t u; float f; } v; v.u = u & 0xffff0000u; return v.f;
}
static __device__ __forceinline__ uint32_t pack2(float lo, float hi) {
    return ((uint32_t)f2bf(hi) << 16) | (uint32_t)f2bf(lo);
}
static __device__ __forceinline__ short8 frag8(const float* p) {
    short8 r;
#pragma unroll
    for (int j = 0; j < 8; ++j) r[j] = (short)f2bf(p[j]);
    return r;
}

// =====================================================================
// kernel 1: MFMA prep — time-MLP + proj + gates -> packed (a,b)
// block = 256 thr (4 waves), 4 chunks of 64 positions; grid = 8*Bg
// =====================================================================
union PrepU {
    struct {
        unsigned short te1[64*72];    //  9216 B
        unsigned short tenc[64*72];   //  9216 B
        unsigned short xa[64*40];     //  5120 B
    } p;
    uint32_t ab[2][64*65];            // 33280 B (packed a|b, stride 65)
};

__global__ __launch_bounds__(256, 3) void prep_kernel(
    const float* __restrict__ x, const float* __restrict__ t,
    const float* __restrict__ mtok,
    const float* __restrict__ te_w1, const float* __restrict__ te_b1,
    const float* __restrict__ te_w2, const float* __restrict__ te_b2,
    const float* __restrict__ fpw, const float* __restrict__ fpb,
    const float* __restrict__ bpw, const float* __restrict__ bpb,
    const float* __restrict__ fwz, const float* __restrict__ fbz,
    const float* __restrict__ fwh, const float* __restrict__ fbh,
    const float* __restrict__ bwz, const float* __restrict__ bbz,
    const float* __restrict__ bwh, const float* __restrict__ bbh,
    int b0,
    uint32_t* __restrict__ abf,              // [Bg*64, L] packed (a lo, b hi)
    uint32_t* __restrict__ abb)
{
    __shared__ __align__(16) PrepU u;
    __shared__ __align__(16) unsigned short s_inp[2][64*72];  // 18432 B

    const int tid = threadIdx.x;
    const int w   = tid >> 6;     // wave 0..3
    const int l   = tid & 63;
    const int lq  = l >> 4;       // quad
    const int ln  = l & 15;

    // ---- weight B-fragments (once per block) ----
    short8 bte[2];
    {
        const float* row = te_w2 + (w*16 + ln)*64;
#pragma unroll
        for (int ks = 0; ks < 2; ++ks) bte[ks] = frag8(row + lq*8 + ks*32);
    }
    short8 bpj[2][3];
#pragma unroll
    for (int p = 0; p < 2; ++p) {
        const int g = 2*w + p;
        const float* PW = (g < 4) ? fpw : bpw;
        const float* row = PW + ((g & 3)*16 + ln)*67;
#pragma unroll
        for (int ks = 0; ks < 2; ++ks) {
            float tmp[8];
#pragma unroll
            for (int j = 0; j < 8; ++j) tmp[j] = row[3 + lq*8 + ks*32 + j];
            bpj[p][ks] = frag8(tmp);
        }
        {   // K-step 2: cols 64..66 = x0,x1,mc weights, rest 0
            float tmp[8];
#pragma unroll
            for (int j = 0; j < 8; ++j) tmp[j] = (lq == 0 && j < 3) ? row[j] : 0.f;
            bpj[p][2] = frag8(tmp);
        }
    }
    // gate fragments: wave w -> dir = w>>1, nt-pair = w&1 (both z and h mats)
    const int wdir = w >> 1, wnp = w & 1;
    short8 bgz[2][2], bgh[2][2];
    float bias_gz[2], bias_gh[2];
    {
        const float* WZ = wdir ? bwz : fwz;
        const float* WH = wdir ? bwh : fwh;
        const float* BZ = wdir ? bbz : fbz;
        const float* BH = wdir ? bbh : fbh;
#pragma unroll
        for (int nt2 = 0; nt2 < 2; ++nt2) {
            const int nt = wnp*2 + nt2;
            const float* rz = WZ + (nt*16 + ln)*64;
            const float* rh = WH + (nt*16 + ln)*64;
#pragma unroll
            for (int ks = 0; ks < 2; ++ks) {
                bgz[nt2][ks] = frag8(rz + lq*8 + ks*32);
                bgh[nt2][ks] = frag8(rh + lq*8 + ks*32);
            }
            bias_gz[nt2] = BZ[nt*16 + ln];
            bias_gh[nt2] = BH[nt*16 + ln];
        }
    }
    const float bias_te = te_b2[w*16 + ln];
    float bias_pj[2];
#pragma unroll
    for (int p = 0; p < 2; ++p) {
        const int g = 2*w + p;
        bias_pj[p] = ((g < 4) ? fpb : bpb)[(g & 3)*16 + ln];
    }
    const float mt0 = mtok[0], mt1 = mtok[1];

    const int baseposl = blockIdx.x * 256;   // 4 chunks x 64

#pragma unroll 1
    for (int ch = 0; ch < 4; ++ch) {
        const int chbase = baseposl + ch*64;
        const int ll0   = chbase & 2047;
        const int bl    = chbase >> 11;
        const int gbase = (b0 << 11) + chbase;

        __syncthreads();   // protect u.p writes vs previous writer reads

        // ---- phase 0: stage te1 + xa (zero pad dwords 2..19, data dwords 0..1) ----
        {
            const int pos = tid & 63;
            const float tv = t[gbase + pos];
            const int k0 = (tid >> 6) * 16;                   // wave-uniform
            uint32_t* dst = (uint32_t*)(u.p.te1 + pos*72 + k0);
#pragma unroll
            for (int kk = 0; kk < 16; kk += 2) {
                float v0 = fmaxf(fmaf(tv, te_w1[k0+kk],   te_b1[k0+kk]),   0.f);
                float v1 = fmaxf(fmaf(tv, te_w1[k0+kk+1], te_b1[k0+kk+1]), 0.f);
                dst[kk >> 1] = pack2(v0, v1);
            }
#pragma unroll
            for (int i = tid; i < 64*20; i += 256) {
                if ((i % 20) >= 2) ((uint32_t*)u.p.xa)[i] = 0;
            }
            if (tid < 64) {
                const float* xp = x + (size_t)(gbase + tid)*3;
                const float mc = xp[2];
                const float x0 = (mc == 0.f) ? mt0 : xp[0];
                const float x1 = (mc == 0.f) ? mt1 : xp[1];
                uint32_t* xr = (uint32_t*)(u.p.xa + tid*40);
                xr[0] = pack2(x0, x1);
                xr[1] = pack2(mc, 0.f);
            }
        }
        __syncthreads();

        // ---- GEMM1: tenc = te1 * te_w2^T + b ----
        {
            const int o = w*16 + ln;
#pragma unroll
            for (int mt = 0; mt < 4; ++mt) {
                f32x4 c = {0.f, 0.f, 0.f, 0.f};
#pragma unroll
                for (int ks = 0; ks < 2; ++ks) {
                    const short8 a = *(const short8*)(u.p.te1 + (mt*16+ln)*72 + lq*8 + ks*32);
                    c = MFMA16(a, bte[ks], c);
                }
#pragma unroll
                for (int r = 0; r < 4; ++r) {
                    const int m = mt*16 + lq*4 + r;
                    u.p.tenc[m*72 + o] = f2bf(c[r] + bias_te);
                }
            }
        }
        __syncthreads();

        // ---- GEMM2: inp_{f,b} = [tenc | x3pad] * pw'^T + pb ----
        {
#pragma unroll
            for (int mt = 0; mt < 4; ++mt) {
                short8 a0 = *(const short8*)(u.p.tenc + (mt*16+ln)*72 + lq*8);
                short8 a1 = *(const short8*)(u.p.tenc + (mt*16+ln)*72 + lq*8 + 32);
                short8 a2 = *(const short8*)(u.p.xa   + (mt*16+ln)*40 + lq*8);
#pragma unroll
                for (int p = 0; p < 2; ++p) {
                    const int g = 2*w + p;
                    const int dir = g >> 2;
                    const int o = (g & 3)*16 + ln;
                    f32x4 c = {0.f, 0.f, 0.f, 0.f};
                    c = MFMA16(a0, bpj[p][0], c);
                    c = MFMA16(a1, bpj[p][1], c);
                    c = MFMA16(a2, bpj[p][2], c);
#pragma unroll
                    for (int r = 0; r < 4; ++r) {
                        const int m = mt*16 + lq*4 + r;
                        s_inp[dir][m*72 + o] = f2bf(c[r] + bias_pj[p]);
                    }
                }
            }
        }
        __syncthreads();

        // ---- GEMM3 fused: wave (dir, nt-pair) computes z AND h-tilde, packs (a,b) ----
        // fast-math epilogue: v_rcp instead of full-precision div (err ~1ulp << bf16)
        {
#pragma unroll
            for (int mt = 0; mt < 4; ++mt) {
                const short8 a0 = *(const short8*)(s_inp[wdir] + (mt*16+ln)*72 + lq*8);
                const short8 a1 = *(const short8*)(s_inp[wdir] + (mt*16+ln)*72 + lq*8 + 32);
#pragma unroll
                for (int nt2 = 0; nt2 < 2; ++nt2) {
                    f32x4 cz = {0.f, 0.f, 0.f, 0.f};
                    f32x4 ch2 = {0.f, 0.f, 0.f, 0.f};
                    cz  = MFMA16(a0, bgz[nt2][0], cz);
                    cz  = MFMA16(a1, bgz[nt2][1], cz);
                    ch2 = MFMA16(a0, bgh[nt2][0], ch2);
                    ch2 = MFMA16(a1, bgh[nt2][1], ch2);
                    const int o = (wnp*2 + nt2)*16 + ln;
#pragma unroll
                    for (int r = 0; r < 4; ++r) {
                        const int m = mt*16 + lq*4 + r;
                        const float az = cz[r]  + bias_gz[nt2];
                        const float ah = ch2[r] + bias_gh[nt2];
                        const float z  = __builtin_amdgcn_rcpf(1.f + __expf(-az));
                        const float cc = fminf(fmaxf(ah, -15.f), 15.f);
                        const float e2 = __expf(2.f * cc);
                        const float th = 1.f - 2.f * __builtin_amdgcn_rcpf(e2 + 1.f);
                        u.ab[wdir][m*65 + o] = pack2(1.f - z, z * th);
                    }
                }
            }
        }
        __syncthreads();

        // ---- writer: pure LDS->global transpose, coalesced 256 B stores ----
        {
#pragma unroll 1
            for (int d = 0; d < 2; ++d) {
                uint32_t* dst = (d ? abb : abf) + (size_t)(bl*64)*NL + ll0;
                const uint32_t* src = u.ab[d];
#pragma unroll
                for (int rep = 0; rep < 16; ++rep) {
                    const int idx = rep*256 + tid;
                    const int o = idx >> 6, row = idx & 63;
                    dst[(size_t)o*NL + row] = src[row*65 + o];
                }
            }
        }
    }
}

// =====================================================================
// kernel 2: chunk-parallel scan — block per (dir, row), 256 threads
// 16 LDS segments of 128 positions; per-thread (A,B) composition over 32
// steps, per-h carry scan, apply+write prestates.
// =====================================================================
#define SEG 128
#define SSTR 129   // +1 dword pad: (h*129+x)%32 = (h+x)%32 -> 2 lanes/bank (free)

__global__ __launch_bounds__(256) void scan2_kernel(
    const uint32_t* __restrict__ abf, const uint32_t* __restrict__ abb,
    unsigned short* __restrict__ hf, unsigned short* __restrict__ hb) // [row][l][h] bf16
{
    __shared__ uint32_t s_seg[64*SSTR];                       // 33024 B
    __shared__ float s_A[4][64], s_B[4][64], s_Hin[4][64], s_H[64];

    const int rl  = blockIdx.x >> 1;
    const int dir = blockIdx.x & 1;
    const int tid = threadIdx.x;
    const int h   = tid & 63;
    const int q   = tid >> 6;   // wave index == subchunk index

    const uint32_t* ab = (dir ? abb : abf) + (size_t)rl * 64 * NL;
    unsigned short* out = (dir ? hb : hf) + (size_t)rl * NL * 64;

    if (tid < 64) s_H[tid] = 0.f;
    __syncthreads();

#pragma unroll 1
    for (int si = 0; si < 16; ++si) {
        const int s  = dir ? (15 - si) : si;
        const int l0 = s * SEG;

        // ---- load segment [64 h][128 l]: 8192 dwords = 32 reps x 256 thr ----
#pragma unroll
        for (int rep = 0; rep < 32; ++rep) {
            const int idx = rep*256 + tid;
            const int hh = idx >> 7, xx = idx & 127;
            s_seg[hh*SSTR + xx] = ab[(size_t)hh*NL + l0 + xx];
        }
        __syncthreads();

        // ---- per-thread affine composition over its 32 logical steps ----
        float A = 1.f, Bc = 0.f;
#pragma unroll 1
        for (int i = 0; i < 32; ++i) {
            const int g = q*32 + i;
            const int xx = dir ? (127 - g) : g;
            const uint32_t uab = s_seg[h*SSTR + xx];
            Bc = fmaf(bflo(uab), Bc, bfhi(uab));
            A *= bflo(uab);
        }
        s_A[q][h] = A; s_B[q][h] = Bc;
        __syncthreads();

        // ---- carry scan across the 4 subchunks, chain segment carry ----
        if (tid < 64) {
            float H = s_H[tid];
#pragma unroll
            for (int qq = 0; qq < 4; ++qq) {
                s_Hin[qq][tid] = H;
                H = fmaf(s_A[qq][tid], H, s_B[qq][tid]);
            }
            s_H[tid] = H;
        }
        __syncthreads();

        // ---- apply + write prestates (coalesced 128 B stores) ----
        float hv = s_Hin[q][h];
#pragma unroll 1
        for (int i = 0; i < 32; ++i) {
            const int g = q*32 + i;
            const int xx = dir ? (127 - g) : g;
            const uint32_t uab = s_seg[h*SSTR + xx];
            out[(size_t)(l0 + xx)*64 + h] = f2bf(hv);
            hv = fmaf(bflo(uab), hv, bfhi(uab));
        }
        __syncthreads();   // s_seg reused next segment
    }
}

// =====================================================================
// kernel 3: MFMA head — recompute tenc, [hf|hb|tenc](192) -> 128 relu -> 1
// block = 256 thr, 4 chunks of 64 positions; grid = 8*Bg
// =====================================================================
union HeadU {
    unsigned short te1[64*72];   //  9216 B
    float hid[64*133];           // 34048 B
};

__global__ __launch_bounds__(256, 2) void head_kernel(
    const float* __restrict__ x, const float* __restrict__ t,
    const float* __restrict__ te_w1, const float* __restrict__ te_b1,
    const float* __restrict__ te_w2, const float* __restrict__ te_b2,
    const unsigned short* __restrict__ hf, const unsigned short* __restrict__ hb,
    const float* __restrict__ w1, const float* __restrict__ b1,  // [128,192],[128]
    const float* __restrict__ w2, const float* __restrict__ b2,  // [1,128],[1]
    int b0,
    float* __restrict__ out)
{
    __shared__ __align__(16) unsigned short s_a[64*200];   // 25600 B
    __shared__ __align__(16) HeadU hu;                     // 34048 B
    __shared__ float s_pac[256];

    const int tid = threadIdx.x;
    const int w   = tid >> 6;
    const int l   = tid & 63;
    const int lq  = l >> 4;
    const int ln  = l & 15;

    // ---- W1 fragments + per-lane b1/w2 + te_w2 fragments ----
    short8 bw1[2][6];
    float b1v[2], w2v[2];
#pragma unroll
    for (int p = 0; p < 2; ++p) {
        const int o = (2*w + p)*16 + ln;
        const float* row = w1 + o*192;
#pragma unroll
        for (int ks = 0; ks < 6; ++ks) bw1[p][ks] = frag8(row + lq*8 + ks*32);
        b1v[p] = b1[o];
        w2v[p] = w2[o];
    }
    short8 bte[2];
    {
        const float* row = te_w2 + (w*16 + ln)*64;
#pragma unroll
        for (int ks = 0; ks < 2; ++ks) bte[ks] = frag8(row + lq*8 + ks*32);
    }
    const float bias_te = te_b2[w*16 + ln];
    const float bias2 = b2[0];

    const int baseposl = blockIdx.x * 256;

#pragma unroll 1
    for (int ch = 0; ch < 4; ++ch) {
        const int chbase = baseposl + ch*64;
        const int ll0   = chbase & 2047;
        const int bl    = chbase >> 11;
        const int gbase = (b0 << 11) + chbase;
        const size_t rowbase = (size_t)bl * NL * 64;

        // ---- stage: hf/hb tiles into s_a cols 0..127, te1 into hu.te1 ----
        {
#pragma unroll 1
            for (int seg = 0; seg < 2; ++seg) {
#pragma unroll
                for (int rep = 0; rep < 8; ++rep) {
                    const int idx = rep*256 + tid;
                    const int row = idx >> 5, c = idx & 31;
                    const float mc = x[(size_t)(gbase + row)*3 + 2];
                    const bool unm = mc > 0.f;
                    const uint32_t* src = (seg == 0)
                        ? (const uint32_t*)(hf + rowbase + (size_t)(unm ? (ll0+row) : (NL-1))*64)
                        : (const uint32_t*)(hb + rowbase + (size_t)(unm ? (ll0+row) : 0)*64);
                    ((uint32_t*)s_a)[row*100 + seg*32 + c] = src[c];
                }
            }
            const int pos = tid & 63;
            const float tv = t[gbase + pos];
            const int k0 = (tid >> 6) * 16;
            uint32_t* dst = (uint32_t*)(hu.te1 + pos*72 + k0);
#pragma unroll
            for (int kk = 0; kk < 16; kk += 2) {
                float v0 = fmaxf(fmaf(tv, te_w1[k0+kk],   te_b1[k0+kk]),   0.f);
                float v1 = fmaxf(fmaf(tv, te_w1[k0+kk+1], te_b1[k0+kk+1]), 0.f);
                dst[kk >> 1] = pack2(v0, v1);
            }
        }
        __syncthreads();

        // ---- tenc GEMM: s_a cols 128..191 = f2bf(te1 * te_w2^T + b) ----
        {
            const int o = w*16 + ln;
#pragma unroll
            for (int mt = 0; mt < 4; ++mt) {
                f32x4 c = {0.f, 0.f, 0.f, 0.f};
#pragma unroll
                for (int ks = 0; ks < 2; ++ks) {
                    const short8 a = *(const short8*)(hu.te1 + (mt*16+ln)*72 + lq*8 + ks*32);
                    c = MFMA16(a, bte[ks], c);
                }
#pragma unroll
                for (int r = 0; r < 4; ++r) {
                    const int m = mt*16 + lq*4 + r;
                    s_a[m*200 + 128 + o] = f2bf(c[r] + bias_te);
                }
            }
        }
        __syncthreads();

        // ---- GEMM1 + premultiplied-hid epilogue (clobbers hu.te1 via union) ----
        {
#pragma unroll
            for (int mt = 0; mt < 4; ++mt) {
                short8 af[6];
#pragma unroll
                for (int ks = 0; ks < 6; ++ks)
                    af[ks] = *(const short8*)(s_a + (mt*16+ln)*200 + lq*8 + ks*32);
#pragma unroll
                for (int p = 0; p < 2; ++p) {
                    f32x4 c = {0.f, 0.f, 0.f, 0.f};
#pragma unroll
                    for (int ks = 0; ks < 6; ++ks) c = MFMA16(af[ks], bw1[p][ks], c);
                    const int o = (2*w + p)*16 + ln;
#pragma unroll
                    for (int r = 0; r < 4; ++r) {
                        const int m = mt*16 + lq*4 + r;
                        hu.hid[m*133 + o] = fmaxf(c[r] + b1v[p], 0.f) * w2v[p];
                    }
                }
            }
        }
        __syncthreads();

        // ---- GEMM2: row sums (4 threads per row, rotated) ----
        {
            const int m = tid >> 2, part = tid & 3;
            const float* hrow = hu.hid + m*133;
            float s = 0.f;
#pragma unroll
            for (int i = 0; i < 32; ++i) {
                const int c = part*32 + ((i + part*8) & 31);
                s += hrow[c];
            }
            s_pac[tid] = s;
        }
        __syncthreads();
        if (tid < 64) {
            out[gbase + tid] = s_pac[tid*4] + s_pac[tid*4+1] + s_pac[tid*4+2] + s_pac[tid*4+3] + bias2;
        }
        __syncthreads();
    }
}

extern "C" void kernel_launch(void* const* d_in, const int* in_sizes, int n_in,
                              void* d_out, int out_size, void* d_ws, size_t ws_size,
                              hipStream_t stream)
{
    const float* x     = (const float*)d_in[0];
    const float* t     = (const float*)d_in[1];
    const float* mtok  = (const float*)d_in[2];
    const float* te_w1 = (const float*)d_in[3];
    const float* te_b1 = (const float*)d_in[4];
    const float* te_w2 = (const float*)d_in[5];
    const float* te_b2 = (const float*)d_in[6];
    const float* fpw   = (const float*)d_in[7];
    const float* fpb   = (const float*)d_in[8];
    const float* bpw   = (const float*)d_in[9];
    const float* bpb   = (const float*)d_in[10];
    const float* fwz   = (const float*)d_in[11];
    const float* fbz   = (const float*)d_in[12];
    const float* fwh   = (const float*)d_in[13];
    const float* fbh   = (const float*)d_in[14];
    const float* bwz   = (const float*)d_in[15];
    const float* bbz   = (const float*)d_in[16];
    const float* bwh   = (const float*)d_in[17];
    const float* bbh   = (const float*)d_in[18];
    const float* w1    = (const float*)d_in[19];
    const float* b1    = (const float*)d_in[20];
    const float* w2    = (const float*)d_in[21];
    const float* b2    = (const float*)d_in[22];

    // Per-batch-row workspace footprint (bytes):
    //   abf+abb : 2 * 64*2048*4 = 1,048,576
    //   hf+hb   : 2 * 2048*64*2 =   524,288
    const size_t per_b = 1572864ull;
    int Bg = NB;
    while ((size_t)Bg * per_b > ws_size && Bg > 1) Bg >>= 1;
    const int nG = NB / Bg;

    char* ws = (char*)d_ws;
    uint32_t*       abf  = (uint32_t*)(ws);
    uint32_t*       abb  = abf + (size_t)Bg * 64 * NL;
    unsigned short* hf   = (unsigned short*)(abb + (size_t)Bg * 64 * NL);
    unsigned short* hb   = hf + (size_t)Bg * NL * 64;

    for (int g = 0; g < nG; ++g) {
        const int b0 = g * Bg;

        prep_kernel<<<8 * Bg, 256, 0, stream>>>(
            x, t, mtok, te_w1, te_b1, te_w2, te_b2,
            fpw, fpb, bpw, bpb, fwz, fbz, fwh, fbh, bwz, bbz, bwh, bbh,
            b0, abf, abb);

        scan2_kernel<<<2 * Bg, 256, 0, stream>>>(abf, abb, hf, hb);

        head_kernel<<<8 * Bg, 256, 0, stream>>>(
            x, t, te_w1, te_b1, te_w2, te_b2,
            hf, hb, w1, b1, w2, b2, b0, (float*)d_out);
    }
}

// Round 9
// 431.389 us; speedup vs baseline: 1.6840x; 1.1037x over previous
//
#include <hip/hip_runtime.h>
#include <stdint.h>

// Problem constants (B=256, L=2048, H=64, TE=64)
#define NB 256
#define NL 2048

typedef __attribute__((ext_vector_type(8))) short short8;
typedef __attribute__((ext_vector_type(4))) float f32x4;
#define MFMA16(a,b,c) __builtin_amdgcn_mfma_f32_16x16x32_bf16(a,b,c,0,0,0)

// ---------- bf16 helpers (manual, RNE) ----------
static __device__ __forceinline__ unsigned short f2bf(float f) {
    union { float f; uint32_t u; } v; v.f = f;
    uint32_t u = v.u;
    uint32_t r = u + 0x7fffu + ((u >> 16) & 1u);
    return (unsigned short)(r >> 16);
}
static __device__ __forceinline__ float bflo(uint32_t u) {
    union { uint32_t u; float f; } v; v.u = u << 16; return v.f;
}
static __device__ __forceinline__ float bfhi(uint32_t u) {
    union { uint32_t u; float f; } v; v.u = u & 0xffff0000u; return v.f;
}
static __device__ __forceinline__ uint32_t pack2(float lo, float hi) {
    return ((uint32_t)f2bf(hi) << 16) | (uint32_t)f2bf(lo);
}
static __device__ __forceinline__ short8 frag8(const float* p) {
    short8 r;
#pragma unroll
    for (int j = 0; j < 8; ++j) r[j] = (short)f2bf(p[j]);
    return r;
}

// =====================================================================
// kernel 1: MFMA prep — time-MLP + proj + gates -> packed (a,b)
// (unchanged from round 8: 476us config, prep ~78us)
// =====================================================================
union PrepU {
    struct {
        unsigned short te1[64*72];    //  9216 B
        unsigned short tenc[64*72];   //  9216 B
        unsigned short xa[64*40];     //  5120 B
    } p;
    uint32_t ab[2][64*65];            // 33280 B (packed a|b, stride 65)
};

__global__ __launch_bounds__(256, 3) void prep_kernel(
    const float* __restrict__ x, const float* __restrict__ t,
    const float* __restrict__ mtok,
    const float* __restrict__ te_w1, const float* __restrict__ te_b1,
    const float* __restrict__ te_w2, const float* __restrict__ te_b2,
    const float* __restrict__ fpw, const float* __restrict__ fpb,
    const float* __restrict__ bpw, const float* __restrict__ bpb,
    const float* __restrict__ fwz, const float* __restrict__ fbz,
    const float* __restrict__ fwh, const float* __restrict__ fbh,
    const float* __restrict__ bwz, const float* __restrict__ bbz,
    const float* __restrict__ bwh, const float* __restrict__ bbh,
    int b0,
    uint32_t* __restrict__ abf,              // [Bg*64, L] packed (a lo, b hi)
    uint32_t* __restrict__ abb)
{
    __shared__ __align__(16) PrepU u;
    __shared__ __align__(16) unsigned short s_inp[2][64*72];  // 18432 B

    const int tid = threadIdx.x;
    const int w   = tid >> 6;     // wave 0..3
    const int l   = tid & 63;
    const int lq  = l >> 4;       // quad
    const int ln  = l & 15;

    short8 bte[2];
    {
        const float* row = te_w2 + (w*16 + ln)*64;
#pragma unroll
        for (int ks = 0; ks < 2; ++ks) bte[ks] = frag8(row + lq*8 + ks*32);
    }
    short8 bpj[2][3];
#pragma unroll
    for (int p = 0; p < 2; ++p) {
        const int g = 2*w + p;
        const float* PW = (g < 4) ? fpw : bpw;
        const float* row = PW + ((g & 3)*16 + ln)*67;
#pragma unroll
        for (int ks = 0; ks < 2; ++ks) {
            float tmp[8];
#pragma unroll
            for (int j = 0; j < 8; ++j) tmp[j] = row[3 + lq*8 + ks*32 + j];
            bpj[p][ks] = frag8(tmp);
        }
        {
            float tmp[8];
#pragma unroll
            for (int j = 0; j < 8; ++j) tmp[j] = (lq == 0 && j < 3) ? row[j] : 0.f;
            bpj[p][2] = frag8(tmp);
        }
    }
    const int wdir = w >> 1, wnp = w & 1;
    short8 bgz[2][2], bgh[2][2];
    float bias_gz[2], bias_gh[2];
    {
        const float* WZ = wdir ? bwz : fwz;
        const float* WH = wdir ? bwh : fwh;
        const float* BZ = wdir ? bbz : fbz;
        const float* BH = wdir ? bbh : fbh;
#pragma unroll
        for (int nt2 = 0; nt2 < 2; ++nt2) {
            const int nt = wnp*2 + nt2;
            const float* rz = WZ + (nt*16 + ln)*64;
            const float* rh = WH + (nt*16 + ln)*64;
#pragma unroll
            for (int ks = 0; ks < 2; ++ks) {
                bgz[nt2][ks] = frag8(rz + lq*8 + ks*32);
                bgh[nt2][ks] = frag8(rh + lq*8 + ks*32);
            }
            bias_gz[nt2] = BZ[nt*16 + ln];
            bias_gh[nt2] = BH[nt*16 + ln];
        }
    }
    const float bias_te = te_b2[w*16 + ln];
    float bias_pj[2];
#pragma unroll
    for (int p = 0; p < 2; ++p) {
        const int g = 2*w + p;
        bias_pj[p] = ((g < 4) ? fpb : bpb)[(g & 3)*16 + ln];
    }
    const float mt0 = mtok[0], mt1 = mtok[1];

    const int baseposl = blockIdx.x * 256;

#pragma unroll 1
    for (int ch = 0; ch < 4; ++ch) {
        const int chbase = baseposl + ch*64;
        const int ll0   = chbase & 2047;
        const int bl    = chbase >> 11;
        const int gbase = (b0 << 11) + chbase;

        __syncthreads();

        {
            const int pos = tid & 63;
            const float tv = t[gbase + pos];
            const int k0 = (tid >> 6) * 16;
            uint32_t* dst = (uint32_t*)(u.p.te1 + pos*72 + k0);
#pragma unroll
            for (int kk = 0; kk < 16; kk += 2) {
                float v0 = fmaxf(fmaf(tv, te_w1[k0+kk],   te_b1[k0+kk]),   0.f);
                float v1 = fmaxf(fmaf(tv, te_w1[k0+kk+1], te_b1[k0+kk+1]), 0.f);
                dst[kk >> 1] = pack2(v0, v1);
            }
#pragma unroll
            for (int i = tid; i < 64*20; i += 256) {
                if ((i % 20) >= 2) ((uint32_t*)u.p.xa)[i] = 0;
            }
            if (tid < 64) {
                const float* xp = x + (size_t)(gbase + tid)*3;
                const float mc = xp[2];
                const float x0 = (mc == 0.f) ? mt0 : xp[0];
                const float x1 = (mc == 0.f) ? mt1 : xp[1];
                uint32_t* xr = (uint32_t*)(u.p.xa + tid*40);
                xr[0] = pack2(x0, x1);
                xr[1] = pack2(mc, 0.f);
            }
        }
        __syncthreads();

        {
            const int o = w*16 + ln;
#pragma unroll
            for (int mt = 0; mt < 4; ++mt) {
                f32x4 c = {0.f, 0.f, 0.f, 0.f};
#pragma unroll
                for (int ks = 0; ks < 2; ++ks) {
                    const short8 a = *(const short8*)(u.p.te1 + (mt*16+ln)*72 + lq*8 + ks*32);
                    c = MFMA16(a, bte[ks], c);
                }
#pragma unroll
                for (int r = 0; r < 4; ++r) {
                    const int m = mt*16 + lq*4 + r;
                    u.p.tenc[m*72 + o] = f2bf(c[r] + bias_te);
                }
            }
        }
        __syncthreads();

        {
#pragma unroll
            for (int mt = 0; mt < 4; ++mt) {
                short8 a0 = *(const short8*)(u.p.tenc + (mt*16+ln)*72 + lq*8);
                short8 a1 = *(const short8*)(u.p.tenc + (mt*16+ln)*72 + lq*8 + 32);
                short8 a2 = *(const short8*)(u.p.xa   + (mt*16+ln)*40 + lq*8);
#pragma unroll
                for (int p = 0; p < 2; ++p) {
                    const int g = 2*w + p;
                    const int dir = g >> 2;
                    const int o = (g & 3)*16 + ln;
                    f32x4 c = {0.f, 0.f, 0.f, 0.f};
                    c = MFMA16(a0, bpj[p][0], c);
                    c = MFMA16(a1, bpj[p][1], c);
                    c = MFMA16(a2, bpj[p][2], c);
#pragma unroll
                    for (int r = 0; r < 4; ++r) {
                        const int m = mt*16 + lq*4 + r;
                        s_inp[dir][m*72 + o] = f2bf(c[r] + bias_pj[p]);
                    }
                }
            }
        }
        __syncthreads();

        {
#pragma unroll
            for (int mt = 0; mt < 4; ++mt) {
                const short8 a0 = *(const short8*)(s_inp[wdir] + (mt*16+ln)*72 + lq*8);
                const short8 a1 = *(const short8*)(s_inp[wdir] + (mt*16+ln)*72 + lq*8 + 32);
#pragma unroll
                for (int nt2 = 0; nt2 < 2; ++nt2) {
                    f32x4 cz = {0.f, 0.f, 0.f, 0.f};
                    f32x4 ch2 = {0.f, 0.f, 0.f, 0.f};
                    cz  = MFMA16(a0, bgz[nt2][0], cz);
                    cz  = MFMA16(a1, bgz[nt2][1], cz);
                    ch2 = MFMA16(a0, bgh[nt2][0], ch2);
                    ch2 = MFMA16(a1, bgh[nt2][1], ch2);
                    const int o = (wnp*2 + nt2)*16 + ln;
#pragma unroll
                    for (int r = 0; r < 4; ++r) {
                        const int m = mt*16 + lq*4 + r;
                        const float az = cz[r]  + bias_gz[nt2];
                        const float ah = ch2[r] + bias_gh[nt2];
                        const float z  = __builtin_amdgcn_rcpf(1.f + __expf(-az));
                        const float cc = fminf(fmaxf(ah, -15.f), 15.f);
                        const float e2 = __expf(2.f * cc);
                        const float th = 1.f - 2.f * __builtin_amdgcn_rcpf(e2 + 1.f);
                        u.ab[wdir][m*65 + o] = pack2(1.f - z, z * th);
                    }
                }
            }
        }
        __syncthreads();

        {
#pragma unroll 1
            for (int d = 0; d < 2; ++d) {
                uint32_t* dst = (d ? abb : abf) + (size_t)(bl*64)*NL + ll0;
                const uint32_t* src = u.ab[d];
#pragma unroll
                for (int rep = 0; rep < 16; ++rep) {
                    const int idx = rep*256 + tid;
                    const int o = idx >> 6, row = idx & 63;
                    dst[(size_t)o*NL + row] = src[row*65 + o];
                }
            }
        }
    }
}

// =====================================================================
// kernel 2: chunk-parallel scan, h-split x2 — block per (row, dir, hhalf)
// 32 h-channels/block, 8 subchunks x 16 steps, register-cached (a,b).
// grid = 4*Bg blocks (2 blk/CU), 16 segments of 128 positions.
// =====================================================================
#define SSTR 129

__global__ __launch_bounds__(256) void scan3_kernel(
    const uint32_t* __restrict__ abf, const uint32_t* __restrict__ abb,
    unsigned short* __restrict__ hf, unsigned short* __restrict__ hb)
{
    __shared__ uint32_t s_seg[32*SSTR];                      // 16512 B
    __shared__ float s_A[8][33], s_B[8][33], s_Hin[8][33];
    __shared__ float s_H[32];

    const int rl  = blockIdx.x >> 2;
    const int dir = (blockIdx.x >> 1) & 1;
    const int h0  = (blockIdx.x & 1) * 32;
    const int tid = threadIdx.x;
    const int h   = tid & 31;
    const int q   = tid >> 5;   // subchunk 0..7

    const uint32_t* ab = (dir ? abb : abf) + (size_t)rl * 64 * NL + (size_t)h0 * NL;
    unsigned short* out = (dir ? hb : hf) + (size_t)rl * NL * 64 + h0;

    if (tid < 32) s_H[tid] = 0.f;
    __syncthreads();

#pragma unroll 1
    for (int si = 0; si < 16; ++si) {
        const int s  = dir ? (15 - si) : si;
        const int l0 = s * 128;

        // ---- load segment [32 h][128 l]: 4096 dwords = 16 reps x 256 thr ----
#pragma unroll
        for (int rep = 0; rep < 16; ++rep) {
            const int idx = rep*256 + tid;
            const int hh = idx >> 7, xx = idx & 127;
            s_seg[hh*SSTR + xx] = ab[(size_t)hh*NL + l0 + xx];
        }
        __syncthreads();

        // ---- compose 16 steps, caching (a,b) in registers ----
        uint32_t regs[16];
        float A = 1.f, Bc = 0.f;
#pragma unroll
        for (int i = 0; i < 16; ++i) {
            const int g = q*16 + i;
            const int xx = dir ? (127 - g) : g;
            const uint32_t uab = s_seg[h*SSTR + xx];
            regs[i] = uab;
            Bc = fmaf(bflo(uab), Bc, bfhi(uab));
            A *= bflo(uab);
        }
        s_A[q][h] = A; s_B[q][h] = Bc;
        __syncthreads();

        // ---- carry scan across 8 subchunks (32 threads) ----
        if (tid < 32) {
            float H = s_H[tid];
#pragma unroll
            for (int qq = 0; qq < 8; ++qq) {
                s_Hin[qq][tid] = H;
                H = fmaf(s_A[qq][tid], H, s_B[qq][tid]);
            }
            s_H[tid] = H;
        }
        __syncthreads();

        // ---- apply + write prestates (64 B contiguous per 32-lane group) ----
        float hv = s_Hin[q][h];
#pragma unroll
        for (int i = 0; i < 16; ++i) {
            const int g = q*16 + i;
            const int xx = dir ? (127 - g) : g;
            const uint32_t uab = regs[i];
            out[(size_t)(l0 + xx)*64 + h] = f2bf(hv);
            hv = fmaf(bflo(uab), hv, bfhi(uab));
        }
        __syncthreads();   // s_seg/s_H reuse next segment
    }
}

// =====================================================================
// kernel 3: MFMA head — recompute tenc, [hf|hb|tenc](192) -> 128 relu -> 1
// shuffle-reduce epilogue (no hid LDS); LDS ~36 KB
// =====================================================================
__global__ __launch_bounds__(256, 3) void head_kernel(
    const float* __restrict__ x, const float* __restrict__ t,
    const float* __restrict__ te_w1, const float* __restrict__ te_b1,
    const float* __restrict__ te_w2, const float* __restrict__ te_b2,
    const unsigned short* __restrict__ hf, const unsigned short* __restrict__ hb,
    const float* __restrict__ w1, const float* __restrict__ b1,  // [128,192],[128]
    const float* __restrict__ w2, const float* __restrict__ b2,  // [1,128],[1]
    int b0,
    float* __restrict__ out)
{
    __shared__ __align__(16) unsigned short s_a[64*200];   // 25600 B
    __shared__ __align__(16) unsigned short s_te1[64*72];  //  9216 B
    __shared__ float s_part[4][64];                        //  1024 B

    const int tid = threadIdx.x;
    const int w   = tid >> 6;
    const int l   = tid & 63;
    const int lq  = l >> 4;
    const int ln  = l & 15;

    short8 bw1[2][6];
    float b1v[2], w2v[2];
#pragma unroll
    for (int p = 0; p < 2; ++p) {
        const int o = (2*w + p)*16 + ln;
        const float* row = w1 + o*192;
#pragma unroll
        for (int ks = 0; ks < 6; ++ks) bw1[p][ks] = frag8(row + lq*8 + ks*32);
        b1v[p] = b1[o];
        w2v[p] = w2[o];
    }
    short8 bte[2];
    {
        const float* row = te_w2 + (w*16 + ln)*64;
#pragma unroll
        for (int ks = 0; ks < 2; ++ks) bte[ks] = frag8(row + lq*8 + ks*32);
    }
    const float bias_te = te_b2[w*16 + ln];
    const float bias2 = b2[0];

    const int baseposl = blockIdx.x * 256;

#pragma unroll 1
    for (int ch = 0; ch < 4; ++ch) {
        const int chbase = baseposl + ch*64;
        const int ll0   = chbase & 2047;
        const int bl    = chbase >> 11;
        const int gbase = (b0 << 11) + chbase;
        const size_t rowbase = (size_t)bl * NL * 64;

        // ---- stage hf/hb tiles + te1 ----
        {
#pragma unroll 1
            for (int seg = 0; seg < 2; ++seg) {
#pragma unroll
                for (int rep = 0; rep < 8; ++rep) {
                    const int idx = rep*256 + tid;
                    const int row = idx >> 5, c = idx & 31;
                    const float mc = x[(size_t)(gbase + row)*3 + 2];
                    const bool unm = mc > 0.f;
                    const uint32_t* src = (seg == 0)
                        ? (const uint32_t*)(hf + rowbase + (size_t)(unm ? (ll0+row) : (NL-1))*64)
                        : (const uint32_t*)(hb + rowbase + (size_t)(unm ? (ll0+row) : 0)*64);
                    ((uint32_t*)s_a)[row*100 + seg*32 + c] = src[c];
                }
            }
            const int pos = tid & 63;
            const float tv = t[gbase + pos];
            const int k0 = (tid >> 6) * 16;
            uint32_t* dst = (uint32_t*)(s_te1 + pos*72 + k0);
#pragma unroll
            for (int kk = 0; kk < 16; kk += 2) {
                float v0 = fmaxf(fmaf(tv, te_w1[k0+kk],   te_b1[k0+kk]),   0.f);
                float v1 = fmaxf(fmaf(tv, te_w1[k0+kk+1], te_b1[k0+kk+1]), 0.f);
                dst[kk >> 1] = pack2(v0, v1);
            }
        }
        __syncthreads();

        // ---- tenc GEMM -> s_a cols 128..191 ----
        {
            const int o = w*16 + ln;
#pragma unroll
            for (int mt = 0; mt < 4; ++mt) {
                f32x4 c = {0.f, 0.f, 0.f, 0.f};
#pragma unroll
                for (int ks = 0; ks < 2; ++ks) {
                    const short8 a = *(const short8*)(s_te1 + (mt*16+ln)*72 + lq*8 + ks*32);
                    c = MFMA16(a, bte[ks], c);
                }
#pragma unroll
                for (int r = 0; r < 4; ++r) {
                    const int m = mt*16 + lq*4 + r;
                    s_a[m*200 + 128 + o] = f2bf(c[r] + bias_te);
                }
            }
        }
        __syncthreads();

        // ---- GEMM1 + in-register relu*w2 + quad shuffle-reduce ----
        {
#pragma unroll
            for (int mt = 0; mt < 4; ++mt) {
                short8 af[6];
#pragma unroll
                for (int ks = 0; ks < 6; ++ks)
                    af[ks] = *(const short8*)(s_a + (mt*16+ln)*200 + lq*8 + ks*32);
                float vs[4] = {0.f, 0.f, 0.f, 0.f};
#pragma unroll
                for (int p = 0; p < 2; ++p) {
                    f32x4 c = {0.f, 0.f, 0.f, 0.f};
#pragma unroll
                    for (int ks = 0; ks < 6; ++ks) c = MFMA16(af[ks], bw1[p][ks], c);
#pragma unroll
                    for (int r = 0; r < 4; ++r)
                        vs[r] += fmaxf(c[r] + b1v[p], 0.f) * w2v[p];
                }
                // sum across the 16 lanes of the quad (ln dimension)
#pragma unroll
                for (int mask = 1; mask < 16; mask <<= 1) {
#pragma unroll
                    for (int r = 0; r < 4; ++r)
                        vs[r] += __shfl_xor(vs[r], mask);
                }
                if (ln == 0) {
#pragma unroll
                    for (int r = 0; r < 4; ++r)
                        s_part[w][mt*16 + lq*4 + r] = vs[r];
                }
            }
        }
        __syncthreads();

        if (tid < 64) {
            out[gbase + tid] = s_part[0][tid] + s_part[1][tid]
                             + s_part[2][tid] + s_part[3][tid] + bias2;
        }
        __syncthreads();
    }
}

extern "C" void kernel_launch(void* const* d_in, const int* in_sizes, int n_in,
                              void* d_out, int out_size, void* d_ws, size_t ws_size,
                              hipStream_t stream)
{
    const float* x     = (const float*)d_in[0];
    const float* t     = (const float*)d_in[1];
    const float* mtok  = (const float*)d_in[2];
    const float* te_w1 = (const float*)d_in[3];
    const float* te_b1 = (const float*)d_in[4];
    const float* te_w2 = (const float*)d_in[5];
    const float* te_b2 = (const float*)d_in[6];
    const float* fpw   = (const float*)d_in[7];
    const float* fpb   = (const float*)d_in[8];
    const float* bpw   = (const float*)d_in[9];
    const float* bpb   = (const float*)d_in[10];
    const float* fwz   = (const float*)d_in[11];
    const float* fbz   = (const float*)d_in[12];
    const float* fwh   = (const float*)d_in[13];
    const float* fbh   = (const float*)d_in[14];
    const float* bwz   = (const float*)d_in[15];
    const float* bbz   = (const float*)d_in[16];
    const float* bwh   = (const float*)d_in[17];
    const float* bbh   = (const float*)d_in[18];
    const float* w1    = (const float*)d_in[19];
    const float* b1    = (const float*)d_in[20];
    const float* w2    = (const float*)d_in[21];
    const float* b2    = (const float*)d_in[22];

    const size_t per_b = 1572864ull;
    int Bg = NB;
    while ((size_t)Bg * per_b > ws_size && Bg > 1) Bg >>= 1;
    const int nG = NB / Bg;

    char* ws = (char*)d_ws;
    uint32_t*       abf  = (uint32_t*)(ws);
    uint32_t*       abb  = abf + (size_t)Bg * 64 * NL;
    unsigned short* hf   = (unsigned short*)(abb + (size_t)Bg * 64 * NL);
    unsigned short* hb   = hf + (size_t)Bg * NL * 64;

    for (int g = 0; g < nG; ++g) {
        const int b0 = g * Bg;

        prep_kernel<<<8 * Bg, 256, 0, stream>>>(
            x, t, mtok, te_w1, te_b1, te_w2, te_b2,
            fpw, fpb, bpw, bpb, fwz, fbz, fwh, fbh, bwz, bbz, bwh, bbh,
            b0, abf, abb);

        scan3_kernel<<<4 * Bg, 256, 0, stream>>>(abf, abb, hf, hb);

        head_kernel<<<8 * Bg, 256, 0, stream>>>(
            x, t, te_w1, te_b1, te_w2, te_b2,
            hf, hb, w1, b1, w2, b2, b0, (float*)d_out);
    }
}

// Round 11
// 429.348 us; speedup vs baseline: 1.6920x; 1.0048x over previous
//
#include <hip/hip_runtime.h>
#include <stdint.h>

// Problem constants (B=256, L=2048, H=64, TE=64)
#define NB 256
#define NL 2048

typedef __attribute__((ext_vector_type(8))) short short8;
typedef __attribute__((ext_vector_type(4))) float f32x4;
#define MFMA16(a,b,c) __builtin_amdgcn_mfma_f32_16x16x32_bf16(a,b,c,0,0,0)

// ---------- bf16 helpers ----------
// R10 post-mortem: W-as-A operand swap caused replay-divergence + slowdown —
// reverted. HW packed cvt kept ONLY at sites already pair-packed in R9.
static __device__ __forceinline__ unsigned short f2bf(float f) {
    union { float f; uint32_t u; } v; v.f = f;
    uint32_t u = v.u;
    uint32_t r = u + 0x7fffu + ((u >> 16) & 1u);
    return (unsigned short)(r >> 16);
}
static __device__ __forceinline__ float bflo(uint32_t u) {
    union { uint32_t u; float f; } v; v.u = u << 16; return v.f;
}
static __device__ __forceinline__ float bfhi(uint32_t u) {
    union { uint32_t u; float f; } v; v.u = u & 0xffff0000u; return v.f;
}
#if __has_builtin(__builtin_amdgcn_cvt_pk_bf16_f32)
typedef __attribute__((ext_vector_type(2))) __bf16 bf16x2_t;
static __device__ __forceinline__ uint32_t pk2(float lo, float hi) {
    union { bf16x2_t v; uint32_t u; } c;
    c.v = __builtin_amdgcn_cvt_pk_bf16_f32(lo, hi);
    return c.u;
}
#else
static __device__ __forceinline__ uint32_t pk2(float lo, float hi) {
    return ((uint32_t)f2bf(hi) << 16) | (uint32_t)f2bf(lo);
}
#endif
static __device__ __forceinline__ short8 frag8(const float* p) {
    short8 r;
#pragma unroll
    for (int j = 0; j < 8; ++j) r[j] = (short)f2bf(p[j]);
    return r;
}

// =====================================================================
// kernel 1: MFMA prep — time-MLP + proj + gates -> packed (a,b)
// (R9 structure: X-as-A operand order, b16-single epilogues for GEMM1/2)
// =====================================================================
union PrepU {
    struct {
        unsigned short te1[64*72];    //  9216 B
        unsigned short tenc[64*72];   //  9216 B
        unsigned short xa[64*40];     //  5120 B
    } p;
    uint32_t ab[2][64*65];            // 33280 B (packed a|b, stride 65)
};

__global__ __launch_bounds__(256, 3) void prep_kernel(
    const float* __restrict__ x, const float* __restrict__ t,
    const float* __restrict__ mtok,
    const float* __restrict__ te_w1, const float* __restrict__ te_b1,
    const float* __restrict__ te_w2, const float* __restrict__ te_b2,
    const float* __restrict__ fpw, const float* __restrict__ fpb,
    const float* __restrict__ bpw, const float* __restrict__ bpb,
    const float* __restrict__ fwz, const float* __restrict__ fbz,
    const float* __restrict__ fwh, const float* __restrict__ fbh,
    const float* __restrict__ bwz, const float* __restrict__ bbz,
    const float* __restrict__ bwh, const float* __restrict__ bbh,
    int b0,
    uint32_t* __restrict__ abf,              // [Bg*64, L] packed (a lo, b hi)
    uint32_t* __restrict__ abb)
{
    __shared__ __align__(16) PrepU u;
    __shared__ __align__(16) unsigned short s_inp[2][64*72];  // 18432 B

    const int tid = threadIdx.x;
    const int w   = tid >> 6;     // wave 0..3
    const int l   = tid & 63;
    const int lq  = l >> 4;       // quad
    const int ln  = l & 15;

    short8 bte[2];
    {
        const float* row = te_w2 + (w*16 + ln)*64;
#pragma unroll
        for (int ks = 0; ks < 2; ++ks) bte[ks] = frag8(row + lq*8 + ks*32);
    }
    short8 bpj[2][3];
#pragma unroll
    for (int p = 0; p < 2; ++p) {
        const int g = 2*w + p;
        const float* PW = (g < 4) ? fpw : bpw;
        const float* row = PW + ((g & 3)*16 + ln)*67;
#pragma unroll
        for (int ks = 0; ks < 2; ++ks) {
            float tmp[8];
#pragma unroll
            for (int j = 0; j < 8; ++j) tmp[j] = row[3 + lq*8 + ks*32 + j];
            bpj[p][ks] = frag8(tmp);
        }
        {
            float tmp[8];
#pragma unroll
            for (int j = 0; j < 8; ++j) tmp[j] = (lq == 0 && j < 3) ? row[j] : 0.f;
            bpj[p][2] = frag8(tmp);
        }
    }
    const int wdir = w >> 1, wnp = w & 1;
    short8 bgz[2][2], bgh[2][2];
    float bias_gz[2], bias_gh[2];
    {
        const float* WZ = wdir ? bwz : fwz;
        const float* WH = wdir ? bwh : fwh;
        const float* BZ = wdir ? bbz : fbz;
        const float* BH = wdir ? bbh : fbh;
#pragma unroll
        for (int nt2 = 0; nt2 < 2; ++nt2) {
            const int nt = wnp*2 + nt2;
            const float* rz = WZ + (nt*16 + ln)*64;
            const float* rh = WH + (nt*16 + ln)*64;
#pragma unroll
            for (int ks = 0; ks < 2; ++ks) {
                bgz[nt2][ks] = frag8(rz + lq*8 + ks*32);
                bgh[nt2][ks] = frag8(rh + lq*8 + ks*32);
            }
            bias_gz[nt2] = BZ[nt*16 + ln];
            bias_gh[nt2] = BH[nt*16 + ln];
        }
    }
    const float bias_te = te_b2[w*16 + ln];
    float bias_pj[2];
#pragma unroll
    for (int p = 0; p < 2; ++p) {
        const int g = 2*w + p;
        bias_pj[p] = ((g < 4) ? fpb : bpb)[(g & 3)*16 + ln];
    }
    const float mt0 = mtok[0], mt1 = mtok[1];

    const int baseposl = blockIdx.x * 256;

#pragma unroll 1
    for (int ch = 0; ch < 4; ++ch) {
        const int chbase = baseposl + ch*64;
        const int ll0   = chbase & 2047;
        const int bl    = chbase >> 11;
        const int gbase = (b0 << 11) + chbase;

        __syncthreads();   // protect u.p writes vs previous writer reads

        // ---- phase 0: stage te1 + xa ----
        {
            const int pos = tid & 63;
            const float tv = t[gbase + pos];
            const int k0 = (tid >> 6) * 16;
            uint32_t* dst = (uint32_t*)(u.p.te1 + pos*72 + k0);
#pragma unroll
            for (int kk = 0; kk < 16; kk += 2) {
                float v0 = fmaxf(fmaf(tv, te_w1[k0+kk],   te_b1[k0+kk]),   0.f);
                float v1 = fmaxf(fmaf(tv, te_w1[k0+kk+1], te_b1[k0+kk+1]), 0.f);
                dst[kk >> 1] = pk2(v0, v1);
            }
#pragma unroll
            for (int i = tid; i < 64*20; i += 256) {
                if ((i % 20) >= 2) ((uint32_t*)u.p.xa)[i] = 0;
            }
            if (tid < 64) {
                const float* xp = x + (size_t)(gbase + tid)*3;
                const float mc = xp[2];
                const float x0 = (mc == 0.f) ? mt0 : xp[0];
                const float x1 = (mc == 0.f) ? mt1 : xp[1];
                uint32_t* xr = (uint32_t*)(u.p.xa + tid*40);
                xr[0] = pk2(x0, x1);
                xr[1] = pk2(mc, 0.f);
            }
        }
        __syncthreads();

        // ---- GEMM1: tenc = te1 * te_w2^T + b ----
        {
            const int o = w*16 + ln;
#pragma unroll
            for (int mt = 0; mt < 4; ++mt) {
                f32x4 c = {0.f, 0.f, 0.f, 0.f};
#pragma unroll
                for (int ks = 0; ks < 2; ++ks) {
                    const short8 a = *(const short8*)(u.p.te1 + (mt*16+ln)*72 + lq*8 + ks*32);
                    c = MFMA16(a, bte[ks], c);
                }
#pragma unroll
                for (int r = 0; r < 4; ++r) {
                    const int m = mt*16 + lq*4 + r;
                    u.p.tenc[m*72 + o] = f2bf(c[r] + bias_te);
                }
            }
        }
        __syncthreads();

        // ---- GEMM2: inp_{f,b} = [tenc | x3pad] * pw'^T + pb ----
        {
#pragma unroll
            for (int mt = 0; mt < 4; ++mt) {
                short8 a0 = *(const short8*)(u.p.tenc + (mt*16+ln)*72 + lq*8);
                short8 a1 = *(const short8*)(u.p.tenc + (mt*16+ln)*72 + lq*8 + 32);
                short8 a2 = *(const short8*)(u.p.xa   + (mt*16+ln)*40 + lq*8);
#pragma unroll
                for (int p = 0; p < 2; ++p) {
                    const int g = 2*w + p;
                    const int dir = g >> 2;
                    const int o = (g & 3)*16 + ln;
                    f32x4 c = {0.f, 0.f, 0.f, 0.f};
                    c = MFMA16(a0, bpj[p][0], c);
                    c = MFMA16(a1, bpj[p][1], c);
                    c = MFMA16(a2, bpj[p][2], c);
#pragma unroll
                    for (int r = 0; r < 4; ++r) {
                        const int m = mt*16 + lq*4 + r;
                        s_inp[dir][m*72 + o] = f2bf(c[r] + bias_pj[p]);
                    }
                }
            }
        }
        __syncthreads();

        // ---- GEMM3 fused: wave (dir, nt-pair) computes z AND h-tilde, packs (a,b) ----
        {
#pragma unroll
            for (int mt = 0; mt < 4; ++mt) {
                const short8 a0 = *(const short8*)(s_inp[wdir] + (mt*16+ln)*72 + lq*8);
                const short8 a1 = *(const short8*)(s_inp[wdir] + (mt*16+ln)*72 + lq*8 + 32);
#pragma unroll
                for (int nt2 = 0; nt2 < 2; ++nt2) {
                    f32x4 cz = {0.f, 0.f, 0.f, 0.f};
                    f32x4 ch2 = {0.f, 0.f, 0.f, 0.f};
                    cz  = MFMA16(a0, bgz[nt2][0], cz);
                    cz  = MFMA16(a1, bgz[nt2][1], cz);
                    ch2 = MFMA16(a0, bgh[nt2][0], ch2);
                    ch2 = MFMA16(a1, bgh[nt2][1], ch2);
                    const int o = (wnp*2 + nt2)*16 + ln;
#pragma unroll
                    for (int r = 0; r < 4; ++r) {
                        const int m = mt*16 + lq*4 + r;
                        const float az = cz[r]  + bias_gz[nt2];
                        const float ah = ch2[r] + bias_gh[nt2];
                        const float z  = __builtin_amdgcn_rcpf(1.f + __expf(-az));
                        const float cc = fminf(fmaxf(ah, -15.f), 15.f);
                        const float e2 = __expf(2.f * cc);
                        const float th = 1.f - 2.f * __builtin_amdgcn_rcpf(e2 + 1.f);
                        u.ab[wdir][m*65 + o] = pk2(1.f - z, z * th);
                    }
                }
            }
        }
        __syncthreads();

        // ---- writer: pure LDS->global transpose, coalesced 256 B stores ----
        {
#pragma unroll 1
            for (int d = 0; d < 2; ++d) {
                uint32_t* dst = (d ? abb : abf) + (size_t)(bl*64)*NL + ll0;
                const uint32_t* src = u.ab[d];
#pragma unroll
                for (int rep = 0; rep < 16; ++rep) {
                    const int idx = rep*256 + tid;
                    const int o = idx >> 6, row = idx & 63;
                    dst[(size_t)o*NL + row] = src[row*65 + o];
                }
            }
        }
    }
}

// =====================================================================
// kernel 2: chunk-parallel scan, h-split x2 (unchanged from R9)
// =====================================================================
#define SSTR 129

__global__ __launch_bounds__(256) void scan3_kernel(
    const uint32_t* __restrict__ abf, const uint32_t* __restrict__ abb,
    unsigned short* __restrict__ hf, unsigned short* __restrict__ hb)
{
    __shared__ uint32_t s_seg[32*SSTR];
    __shared__ float s_A[8][33], s_B[8][33], s_Hin[8][33];
    __shared__ float s_H[32];

    const int rl  = blockIdx.x >> 2;
    const int dir = (blockIdx.x >> 1) & 1;
    const int h0  = (blockIdx.x & 1) * 32;
    const int tid = threadIdx.x;
    const int h   = tid & 31;
    const int q   = tid >> 5;

    const uint32_t* ab = (dir ? abb : abf) + (size_t)rl * 64 * NL + (size_t)h0 * NL;
    unsigned short* out = (dir ? hb : hf) + (size_t)rl * NL * 64 + h0;

    if (tid < 32) s_H[tid] = 0.f;
    __syncthreads();

#pragma unroll 1
    for (int si = 0; si < 16; ++si) {
        const int s  = dir ? (15 - si) : si;
        const int l0 = s * 128;

#pragma unroll
        for (int rep = 0; rep < 16; ++rep) {
            const int idx = rep*256 + tid;
            const int hh = idx >> 7, xx = idx & 127;
            s_seg[hh*SSTR + xx] = ab[(size_t)hh*NL + l0 + xx];
        }
        __syncthreads();

        uint32_t regs[16];
        float A = 1.f, Bc = 0.f;
#pragma unroll
        for (int i = 0; i < 16; ++i) {
            const int g = q*16 + i;
            const int xx = dir ? (127 - g) : g;
            const uint32_t uab = s_seg[h*SSTR + xx];
            regs[i] = uab;
            Bc = fmaf(bflo(uab), Bc, bfhi(uab));
            A *= bflo(uab);
        }
        s_A[q][h] = A; s_B[q][h] = Bc;
        __syncthreads();

        if (tid < 32) {
            float H = s_H[tid];
#pragma unroll
            for (int qq = 0; qq < 8; ++qq) {
                s_Hin[qq][tid] = H;
                H = fmaf(s_A[qq][tid], H, s_B[qq][tid]);
            }
            s_H[tid] = H;
        }
        __syncthreads();

        float hv = s_Hin[q][h];
#pragma unroll
        for (int i = 0; i < 16; ++i) {
            const int g = q*16 + i;
            const int xx = dir ? (127 - g) : g;
            const uint32_t uab = regs[i];
            out[(size_t)(l0 + xx)*64 + h] = f2bf(hv);
            hv = fmaf(bflo(uab), hv, bfhi(uab));
        }
        __syncthreads();
    }
}

// =====================================================================
// kernel 3: MFMA head — recompute tenc, GEMM1 + shuffle-reduce (R9 form)
// =====================================================================
__global__ __launch_bounds__(256, 3) void head_kernel(
    const float* __restrict__ x, const float* __restrict__ t,
    const float* __restrict__ te_w1, const float* __restrict__ te_b1,
    const float* __restrict__ te_w2, const float* __restrict__ te_b2,
    const unsigned short* __restrict__ hf, const unsigned short* __restrict__ hb,
    const float* __restrict__ w1, const float* __restrict__ b1,
    const float* __restrict__ w2, const float* __restrict__ b2,
    int b0,
    float* __restrict__ out)
{
    __shared__ __align__(16) unsigned short s_a[64*200];
    __shared__ __align__(16) unsigned short s_te1[64*72];
    __shared__ float s_part[4][64];

    const int tid = threadIdx.x;
    const int w   = tid >> 6;
    const int l   = tid & 63;
    const int lq  = l >> 4;
    const int ln  = l & 15;

    short8 bw1[2][6];
    float b1v[2], w2v[2];
#pragma unroll
    for (int p = 0; p < 2; ++p) {
        const int o = (2*w + p)*16 + ln;
        const float* row = w1 + o*192;
#pragma unroll
        for (int ks = 0; ks < 6; ++ks) bw1[p][ks] = frag8(row + lq*8 + ks*32);
        b1v[p] = b1[o];
        w2v[p] = w2[o];
    }
    short8 bte[2];
    {
        const float* row = te_w2 + (w*16 + ln)*64;
#pragma unroll
        for (int ks = 0; ks < 2; ++ks) bte[ks] = frag8(row + lq*8 + ks*32);
    }
    const float bias_te = te_b2[w*16 + ln];
    const float bias2 = b2[0];

    const int baseposl = blockIdx.x * 256;

#pragma unroll 1
    for (int ch = 0; ch < 4; ++ch) {
        const int chbase = baseposl + ch*64;
        const int ll0   = chbase & 2047;
        const int bl    = chbase >> 11;
        const int gbase = (b0 << 11) + chbase;
        const size_t rowbase = (size_t)bl * NL * 64;

        {
#pragma unroll 1
            for (int seg = 0; seg < 2; ++seg) {
#pragma unroll
                for (int rep = 0; rep < 8; ++rep) {
                    const int idx = rep*256 + tid;
                    const int row = idx >> 5, c = idx & 31;
                    const float mc = x[(size_t)(gbase + row)*3 + 2];
                    const bool unm = mc > 0.f;
                    const uint32_t* src = (seg == 0)
                        ? (const uint32_t*)(hf + rowbase + (size_t)(unm ? (ll0+row) : (NL-1))*64)
                        : (const uint32_t*)(hb + rowbase + (size_t)(unm ? (ll0+row) : 0)*64);
                    ((uint32_t*)s_a)[row*100 + seg*32 + c] = src[c];
                }
            }
            const int pos = tid & 63;
            const float tv = t[gbase + pos];
            const int k0 = (tid >> 6) * 16;
            uint32_t* dst = (uint32_t*)(s_te1 + pos*72 + k0);
#pragma unroll
            for (int kk = 0; kk < 16; kk += 2) {
                float v0 = fmaxf(fmaf(tv, te_w1[k0+kk],   te_b1[k0+kk]),   0.f);
                float v1 = fmaxf(fmaf(tv, te_w1[k0+kk+1], te_b1[k0+kk+1]), 0.f);
                dst[kk >> 1] = pk2(v0, v1);
            }
        }
        __syncthreads();

        // ---- tenc GEMM -> s_a cols 128..191 (R9 form) ----
        {
            const int o = w*16 + ln;
#pragma unroll
            for (int mt = 0; mt < 4; ++mt) {
                f32x4 c = {0.f, 0.f, 0.f, 0.f};
#pragma unroll
                for (int ks = 0; ks < 2; ++ks) {
                    const short8 a = *(const short8*)(s_te1 + (mt*16+ln)*72 + lq*8 + ks*32);
                    c = MFMA16(a, bte[ks], c);
                }
#pragma unroll
                for (int r = 0; r < 4; ++r) {
                    const int m = mt*16 + lq*4 + r;
                    s_a[m*200 + 128 + o] = f2bf(c[r] + bias_te);
                }
            }
        }
        __syncthreads();

        // ---- GEMM1 + in-register relu*w2 + quad shuffle-reduce ----
        {
#pragma unroll
            for (int mt = 0; mt < 4; ++mt) {
                short8 af[6];
#pragma unroll
                for (int ks = 0; ks < 6; ++ks)
                    af[ks] = *(const short8*)(s_a + (mt*16+ln)*200 + lq*8 + ks*32);
                float vs[4] = {0.f, 0.f, 0.f, 0.f};
#pragma unroll
                for (int p = 0; p < 2; ++p) {
                    f32x4 c = {0.f, 0.f, 0.f, 0.f};
#pragma unroll
                    for (int ks = 0; ks < 6; ++ks) c = MFMA16(af[ks], bw1[p][ks], c);
#pragma unroll
                    for (int r = 0; r < 4; ++r)
                        vs[r] += fmaxf(c[r] + b1v[p], 0.f) * w2v[p];
                }
#pragma unroll
                for (int mask = 1; mask < 16; mask <<= 1) {
#pragma unroll
                    for (int r = 0; r < 4; ++r)
                        vs[r] += __shfl_xor(vs[r], mask);
                }
                if (ln == 0) {
#pragma unroll
                    for (int r = 0; r < 4; ++r)
                        s_part[w][mt*16 + lq*4 + r] = vs[r];
                }
            }
        }
        __syncthreads();

        if (tid < 64) {
            out[gbase + tid] = s_part[0][tid] + s_part[1][tid]
                             + s_part[2][tid] + s_part[3][tid] + bias2;
        }
        __syncthreads();
    }
}

extern "C" void kernel_launch(void* const* d_in, const int* in_sizes, int n_in,
                              void* d_out, int out_size, void* d_ws, size_t ws_size,
                              hipStream_t stream)
{
    const float* x     = (const float*)d_in[0];
    const float* t     = (const float*)d_in[1];
    const float* mtok  = (const float*)d_in[2];
    const float* te_w1 = (const float*)d_in[3];
    const float* te_b1 = (const float*)d_in[4];
    const float* te_w2 = (const float*)d_in[5];
    const float* te_b2 = (const float*)d_in[6];
    const float* fpw   = (const float*)d_in[7];
    const float* fpb   = (const float*)d_in[8];
    const float* bpw   = (const float*)d_in[9];
    const float* bpb   = (const float*)d_in[10];
    const float* fwz   = (const float*)d_in[11];
    const float* fbz   = (const float*)d_in[12];
    const float* fwh   = (const float*)d_in[13];
    const float* fbh   = (const float*)d_in[14];
    const float* bwz   = (const float*)d_in[15];
    const float* bbz   = (const float*)d_in[16];
    const float* bwh   = (const float*)d_in[17];
    const float* bbh   = (const float*)d_in[18];
    const float* w1    = (const float*)d_in[19];
    const float* b1    = (const float*)d_in[20];
    const float* w2    = (const float*)d_in[21];
    const float* b2    = (const float*)d_in[22];

    const size_t per_b = 1572864ull;
    int Bg = NB;
    while ((size_t)Bg * per_b > ws_size && Bg > 1) Bg >>= 1;
    const int nG = NB / Bg;

    char* ws = (char*)d_ws;
    uint32_t*       abf  = (uint32_t*)(ws);
    uint32_t*       abb  = abf + (size_t)Bg * 64 * NL;
    unsigned short* hf   = (unsigned short*)(abb + (size_t)Bg * 64 * NL);
    unsigned short* hb   = hf + (size_t)Bg * NL * 64;

    for (int g = 0; g < nG; ++g) {
        const int b0 = g * Bg;

        prep_kernel<<<8 * Bg, 256, 0, stream>>>(
            x, t, mtok, te_w1, te_b1, te_w2, te_b2,
            fpw, fpb, bpw, bpb, fwz, fbz, fwh, fbh, bwz, bbz, bwh, bbh,
            b0, abf, abb);

        scan3_kernel<<<4 * Bg, 256, 0, stream>>>(abf, abb, hf, hb);

        head_kernel<<<8 * Bg, 256, 0, stream>>>(
            x, t, te_w1, te_b1, te_w2, te_b2,
            hf, hb, w1, b1, w2, b2, b0, (float*)d_out);
    }
}

// Round 12
// 421.500 us; speedup vs baseline: 1.7235x; 1.0186x over previous
//
#include <hip/hip_runtime.h>
#include <stdint.h>

// Problem constants (B=256, L=2048, H=64, TE=64)
#define NB 256
#define NL 2048

typedef __attribute__((ext_vector_type(8))) short short8;
typedef __attribute__((ext_vector_type(4))) float f32x4;
#define MFMA16(a,b,c) __builtin_amdgcn_mfma_f32_16x16x32_bf16(a,b,c,0,0,0)

// ---------- bf16 helpers ----------
// R10 post-mortem: W-as-A operand swap caused replay-divergence — dead.
// pk2 (HW packed cvt) proven safe at pair-packed sites (R11 pass).
static __device__ __forceinline__ unsigned short f2bf(float f) {
    union { float f; uint32_t u; } v; v.f = f;
    uint32_t u = v.u;
    uint32_t r = u + 0x7fffu + ((u >> 16) & 1u);
    return (unsigned short)(r >> 16);
}
static __device__ __forceinline__ float bflo(uint32_t u) {
    union { uint32_t u; float f; } v; v.u = u << 16; return v.f;
}
static __device__ __forceinline__ float bfhi(uint32_t u) {
    union { uint32_t u; float f; } v; v.u = u & 0xffff0000u; return v.f;
}
#if __has_builtin(__builtin_amdgcn_cvt_pk_bf16_f32)
typedef __attribute__((ext_vector_type(2))) __bf16 bf16x2_t;
static __device__ __forceinline__ uint32_t pk2(float lo, float hi) {
    union { bf16x2_t v; uint32_t u; } c;
    c.v = __builtin_amdgcn_cvt_pk_bf16_f32(lo, hi);
    return c.u;
}
#else
static __device__ __forceinline__ uint32_t pk2(float lo, float hi) {
    return ((uint32_t)f2bf(hi) << 16) | (uint32_t)f2bf(lo);
}
#endif
static __device__ __forceinline__ short8 frag8(const float* p) {
    short8 r;
#pragma unroll
    for (int j = 0; j < 8; ++j) r[j] = (short)f2bf(p[j]);
    return r;
}

// =====================================================================
// kernel 1: MFMA prep — time-MLP + proj + gates -> packed (a,b)
// R12: GEMM3 lane owns 4 consecutive m at fixed o == ab[o][l] layout
// -> direct global_store_dwordx4; writer phase + ab LDS union removed.
// LDS 51.7 -> 42 KB.
// =====================================================================
__global__ __launch_bounds__(256, 3) void prep_kernel(
    const float* __restrict__ x, const float* __restrict__ t,
    const float* __restrict__ mtok,
    const float* __restrict__ te_w1, const float* __restrict__ te_b1,
    const float* __restrict__ te_w2, const float* __restrict__ te_b2,
    const float* __restrict__ fpw, const float* __restrict__ fpb,
    const float* __restrict__ bpw, const float* __restrict__ bpb,
    const float* __restrict__ fwz, const float* __restrict__ fbz,
    const float* __restrict__ fwh, const float* __restrict__ fbh,
    const float* __restrict__ bwz, const float* __restrict__ bbz,
    const float* __restrict__ bwh, const float* __restrict__ bbh,
    int b0,
    uint32_t* __restrict__ abf,              // [Bg*64, L] packed (a lo, b hi)
    uint32_t* __restrict__ abb)
{
    __shared__ __align__(16) unsigned short s_te1[64*72];     //  9216 B
    __shared__ __align__(16) unsigned short s_tenc[64*72];    //  9216 B
    __shared__ __align__(16) unsigned short s_xa[64*40];      //  5120 B
    __shared__ __align__(16) unsigned short s_inp[2][64*72];  // 18432 B

    const int tid = threadIdx.x;
    const int w   = tid >> 6;     // wave 0..3
    const int l   = tid & 63;
    const int lq  = l >> 4;       // quad
    const int ln  = l & 15;

    short8 bte[2];
    {
        const float* row = te_w2 + (w*16 + ln)*64;
#pragma unroll
        for (int ks = 0; ks < 2; ++ks) bte[ks] = frag8(row + lq*8 + ks*32);
    }
    short8 bpj[2][3];
#pragma unroll
    for (int p = 0; p < 2; ++p) {
        const int g = 2*w + p;
        const float* PW = (g < 4) ? fpw : bpw;
        const float* row = PW + ((g & 3)*16 + ln)*67;
#pragma unroll
        for (int ks = 0; ks < 2; ++ks) {
            float tmp[8];
#pragma unroll
            for (int j = 0; j < 8; ++j) tmp[j] = row[3 + lq*8 + ks*32 + j];
            bpj[p][ks] = frag8(tmp);
        }
        {
            float tmp[8];
#pragma unroll
            for (int j = 0; j < 8; ++j) tmp[j] = (lq == 0 && j < 3) ? row[j] : 0.f;
            bpj[p][2] = frag8(tmp);
        }
    }
    const int wdir = w >> 1, wnp = w & 1;
    short8 bgz[2][2], bgh[2][2];
    float bias_gz[2], bias_gh[2];
    {
        const float* WZ = wdir ? bwz : fwz;
        const float* WH = wdir ? bwh : fwh;
        const float* BZ = wdir ? bbz : fbz;
        const float* BH = wdir ? bbh : fbh;
#pragma unroll
        for (int nt2 = 0; nt2 < 2; ++nt2) {
            const int nt = wnp*2 + nt2;
            const float* rz = WZ + (nt*16 + ln)*64;
            const float* rh = WH + (nt*16 + ln)*64;
#pragma unroll
            for (int ks = 0; ks < 2; ++ks) {
                bgz[nt2][ks] = frag8(rz + lq*8 + ks*32);
                bgh[nt2][ks] = frag8(rh + lq*8 + ks*32);
            }
            bias_gz[nt2] = BZ[nt*16 + ln];
            bias_gh[nt2] = BH[nt*16 + ln];
        }
    }
    const float bias_te = te_b2[w*16 + ln];
    float bias_pj[2];
#pragma unroll
    for (int p = 0; p < 2; ++p) {
        const int g = 2*w + p;
        bias_pj[p] = ((g < 4) ? fpb : bpb)[(g & 3)*16 + ln];
    }
    const float mt0 = mtok[0], mt1 = mtok[1];

    const int baseposl = blockIdx.x * 256;

#pragma unroll 1
    for (int ch = 0; ch < 4; ++ch) {
        const int chbase = baseposl + ch*64;
        const int ll0   = chbase & 2047;
        const int bl    = chbase >> 11;
        const int gbase = (b0 << 11) + chbase;

        __syncthreads();   // phase0 writes vs prior chunk's reads

        // ---- phase 0: stage te1 + xa ----
        {
            const int pos = tid & 63;
            const float tv = t[gbase + pos];
            const int k0 = (tid >> 6) * 16;
            uint32_t* dst = (uint32_t*)(s_te1 + pos*72 + k0);
#pragma unroll
            for (int kk = 0; kk < 16; kk += 2) {
                float v0 = fmaxf(fmaf(tv, te_w1[k0+kk],   te_b1[k0+kk]),   0.f);
                float v1 = fmaxf(fmaf(tv, te_w1[k0+kk+1], te_b1[k0+kk+1]), 0.f);
                dst[kk >> 1] = pk2(v0, v1);
            }
#pragma unroll
            for (int i = tid; i < 64*20; i += 256) {
                if ((i % 20) >= 2) ((uint32_t*)s_xa)[i] = 0;
            }
            if (tid < 64) {
                const float* xp = x + (size_t)(gbase + tid)*3;
                const float mc = xp[2];
                const float x0 = (mc == 0.f) ? mt0 : xp[0];
                const float x1 = (mc == 0.f) ? mt1 : xp[1];
                uint32_t* xr = (uint32_t*)(s_xa + tid*40);
                xr[0] = pk2(x0, x1);
                xr[1] = pk2(mc, 0.f);
            }
        }
        __syncthreads();

        // ---- GEMM1: tenc = te1 * te_w2^T + b ----
        {
            const int o = w*16 + ln;
#pragma unroll
            for (int mt = 0; mt < 4; ++mt) {
                f32x4 c = {0.f, 0.f, 0.f, 0.f};
#pragma unroll
                for (int ks = 0; ks < 2; ++ks) {
                    const short8 a = *(const short8*)(s_te1 + (mt*16+ln)*72 + lq*8 + ks*32);
                    c = MFMA16(a, bte[ks], c);
                }
#pragma unroll
                for (int r = 0; r < 4; ++r) {
                    const int m = mt*16 + lq*4 + r;
                    s_tenc[m*72 + o] = f2bf(c[r] + bias_te);
                }
            }
        }
        __syncthreads();

        // ---- GEMM2: inp_{f,b} = [tenc | x3pad] * pw'^T + pb ----
        {
#pragma unroll
            for (int mt = 0; mt < 4; ++mt) {
                short8 a0 = *(const short8*)(s_tenc + (mt*16+ln)*72 + lq*8);
                short8 a1 = *(const short8*)(s_tenc + (mt*16+ln)*72 + lq*8 + 32);
                short8 a2 = *(const short8*)(s_xa   + (mt*16+ln)*40 + lq*8);
#pragma unroll
                for (int p = 0; p < 2; ++p) {
                    const int g = 2*w + p;
                    const int dir = g >> 2;
                    const int o = (g & 3)*16 + ln;
                    f32x4 c = {0.f, 0.f, 0.f, 0.f};
                    c = MFMA16(a0, bpj[p][0], c);
                    c = MFMA16(a1, bpj[p][1], c);
                    c = MFMA16(a2, bpj[p][2], c);
#pragma unroll
                    for (int r = 0; r < 4; ++r) {
                        const int m = mt*16 + lq*4 + r;
                        s_inp[dir][m*72 + o] = f2bf(c[r] + bias_pj[p]);
                    }
                }
            }
        }
        __syncthreads();

        // ---- GEMM3 fused: z + h-tilde -> (a,b) packed, DIRECT dwordx4 stores ----
        // lane (lq,ln): o = (wnp*2+nt2)*16+ln fixed, m = mt*16+lq*4+{0..3}
        // global ab[o][l] wants consecutive l at fixed o -> one uint4 store.
        {
            uint32_t* abD = (wdir ? abb : abf) + (size_t)(bl*64)*NL + ll0;
#pragma unroll
            for (int mt = 0; mt < 4; ++mt) {
                const short8 a0 = *(const short8*)(s_inp[wdir] + (mt*16+ln)*72 + lq*8);
                const short8 a1 = *(const short8*)(s_inp[wdir] + (mt*16+ln)*72 + lq*8 + 32);
#pragma unroll
                for (int nt2 = 0; nt2 < 2; ++nt2) {
                    f32x4 cz = {0.f, 0.f, 0.f, 0.f};
                    f32x4 ch2 = {0.f, 0.f, 0.f, 0.f};
                    cz  = MFMA16(a0, bgz[nt2][0], cz);
                    cz  = MFMA16(a1, bgz[nt2][1], cz);
                    ch2 = MFMA16(a0, bgh[nt2][0], ch2);
                    ch2 = MFMA16(a1, bgh[nt2][1], ch2);
                    const int o = (wnp*2 + nt2)*16 + ln;
                    uint4 v;
                    uint32_t* vp = (uint32_t*)&v;
#pragma unroll
                    for (int r = 0; r < 4; ++r) {
                        const float az = cz[r]  + bias_gz[nt2];
                        const float ah = ch2[r] + bias_gh[nt2];
                        const float z  = __builtin_amdgcn_rcpf(1.f + __expf(-az));
                        const float cc = fminf(fmaxf(ah, -15.f), 15.f);
                        const float e2 = __expf(2.f * cc);
                        const float th = 1.f - 2.f * __builtin_amdgcn_rcpf(e2 + 1.f);
                        vp[r] = pk2(1.f - z, z * th);
                    }
                    *(uint4*)(abD + (size_t)o*NL + mt*16 + lq*4) = v;
                }
            }
        }
        // no barrier here: next chunk's top barrier precedes any LDS reuse
    }
}

// =====================================================================
// kernel 2: chunk-parallel scan, h-split x2 (unchanged from R9)
// =====================================================================
#define SSTR 129

__global__ __launch_bounds__(256) void scan3_kernel(
    const uint32_t* __restrict__ abf, const uint32_t* __restrict__ abb,
    unsigned short* __restrict__ hf, unsigned short* __restrict__ hb)
{
    __shared__ uint32_t s_seg[32*SSTR];
    __shared__ float s_A[8][33], s_B[8][33], s_Hin[8][33];
    __shared__ float s_H[32];

    const int rl  = blockIdx.x >> 2;
    const int dir = (blockIdx.x >> 1) & 1;
    const int h0  = (blockIdx.x & 1) * 32;
    const int tid = threadIdx.x;
    const int h   = tid & 31;
    const int q   = tid >> 5;

    const uint32_t* ab = (dir ? abb : abf) + (size_t)rl * 64 * NL + (size_t)h0 * NL;
    unsigned short* out = (dir ? hb : hf) + (size_t)rl * NL * 64 + h0;

    if (tid < 32) s_H[tid] = 0.f;
    __syncthreads();

#pragma unroll 1
    for (int si = 0; si < 16; ++si) {
        const int s  = dir ? (15 - si) : si;
        const int l0 = s * 128;

#pragma unroll
        for (int rep = 0; rep < 16; ++rep) {
            const int idx = rep*256 + tid;
            const int hh = idx >> 7, xx = idx & 127;
            s_seg[hh*SSTR + xx] = ab[(size_t)hh*NL + l0 + xx];
        }
        __syncthreads();

        uint32_t regs[16];
        float A = 1.f, Bc = 0.f;
#pragma unroll
        for (int i = 0; i < 16; ++i) {
            const int g = q*16 + i;
            const int xx = dir ? (127 - g) : g;
            const uint32_t uab = s_seg[h*SSTR + xx];
            regs[i] = uab;
            Bc = fmaf(bflo(uab), Bc, bfhi(uab));
            A *= bflo(uab);
        }
        s_A[q][h] = A; s_B[q][h] = Bc;
        __syncthreads();

        if (tid < 32) {
            float H = s_H[tid];
#pragma unroll
            for (int qq = 0; qq < 8; ++qq) {
                s_Hin[qq][tid] = H;
                H = fmaf(s_A[qq][tid], H, s_B[qq][tid]);
            }
            s_H[tid] = H;
        }
        __syncthreads();

        float hv = s_Hin[q][h];
#pragma unroll
        for (int i = 0; i < 16; ++i) {
            const int g = q*16 + i;
            const int xx = dir ? (127 - g) : g;
            const uint32_t uab = regs[i];
            out[(size_t)(l0 + xx)*64 + h] = f2bf(hv);
            hv = fmaf(bflo(uab), hv, bfhi(uab));
        }
        __syncthreads();
    }
}

// =====================================================================
// kernel 3: MFMA head — recompute tenc, GEMM1 + shuffle-reduce (R9 form)
// =====================================================================
__global__ __launch_bounds__(256, 3) void head_kernel(
    const float* __restrict__ x, const float* __restrict__ t,
    const float* __restrict__ te_w1, const float* __restrict__ te_b1,
    const float* __restrict__ te_w2, const float* __restrict__ te_b2,
    const unsigned short* __restrict__ hf, const unsigned short* __restrict__ hb,
    const float* __restrict__ w1, const float* __restrict__ b1,
    const float* __restrict__ w2, const float* __restrict__ b2,
    int b0,
    float* __restrict__ out)
{
    __shared__ __align__(16) unsigned short s_a[64*200];
    __shared__ __align__(16) unsigned short s_te1[64*72];
    __shared__ float s_part[4][64];

    const int tid = threadIdx.x;
    const int w   = tid >> 6;
    const int l   = tid & 63;
    const int lq  = l >> 4;
    const int ln  = l & 15;

    short8 bw1[2][6];
    float b1v[2], w2v[2];
#pragma unroll
    for (int p = 0; p < 2; ++p) {
        const int o = (2*w + p)*16 + ln;
        const float* row = w1 + o*192;
#pragma unroll
        for (int ks = 0; ks < 6; ++ks) bw1[p][ks] = frag8(row + lq*8 + ks*32);
        b1v[p] = b1[o];
        w2v[p] = w2[o];
    }
    short8 bte[2];
    {
        const float* row = te_w2 + (w*16 + ln)*64;
#pragma unroll
        for (int ks = 0; ks < 2; ++ks) bte[ks] = frag8(row + lq*8 + ks*32);
    }
    const float bias_te = te_b2[w*16 + ln];
    const float bias2 = b2[0];

    const int baseposl = blockIdx.x * 256;

#pragma unroll 1
    for (int ch = 0; ch < 4; ++ch) {
        const int chbase = baseposl + ch*64;
        const int ll0   = chbase & 2047;
        const int bl    = chbase >> 11;
        const int gbase = (b0 << 11) + chbase;
        const size_t rowbase = (size_t)bl * NL * 64;

        {
#pragma unroll 1
            for (int seg = 0; seg < 2; ++seg) {
#pragma unroll
                for (int rep = 0; rep < 8; ++rep) {
                    const int idx = rep*256 + tid;
                    const int row = idx >> 5, c = idx & 31;
                    const float mc = x[(size_t)(gbase + row)*3 + 2];
                    const bool unm = mc > 0.f;
                    const uint32_t* src = (seg == 0)
                        ? (const uint32_t*)(hf + rowbase + (size_t)(unm ? (ll0+row) : (NL-1))*64)
                        : (const uint32_t*)(hb + rowbase + (size_t)(unm ? (ll0+row) : 0)*64);
                    ((uint32_t*)s_a)[row*100 + seg*32 + c] = src[c];
                }
            }
            const int pos = tid & 63;
            const float tv = t[gbase + pos];
            const int k0 = (tid >> 6) * 16;
            uint32_t* dst = (uint32_t*)(s_te1 + pos*72 + k0);
#pragma unroll
            for (int kk = 0; kk < 16; kk += 2) {
                float v0 = fmaxf(fmaf(tv, te_w1[k0+kk],   te_b1[k0+kk]),   0.f);
                float v1 = fmaxf(fmaf(tv, te_w1[k0+kk+1], te_b1[k0+kk+1]), 0.f);
                dst[kk >> 1] = pk2(v0, v1);
            }
        }
        __syncthreads();

        // ---- tenc GEMM -> s_a cols 128..191 ----
        {
            const int o = w*16 + ln;
#pragma unroll
            for (int mt = 0; mt < 4; ++mt) {
                f32x4 c = {0.f, 0.f, 0.f, 0.f};
#pragma unroll
                for (int ks = 0; ks < 2; ++ks) {
                    const short8 a = *(const short8*)(s_te1 + (mt*16+ln)*72 + lq*8 + ks*32);
                    c = MFMA16(a, bte[ks], c);
                }
#pragma unroll
                for (int r = 0; r < 4; ++r) {
                    const int m = mt*16 + lq*4 + r;
                    s_a[m*200 + 128 + o] = f2bf(c[r] + bias_te);
                }
            }
        }
        __syncthreads();

        // ---- GEMM1 + in-register relu*w2 + quad shuffle-reduce ----
        {
#pragma unroll
            for (int mt = 0; mt < 4; ++mt) {
                short8 af[6];
#pragma unroll
                for (int ks = 0; ks < 6; ++ks)
                    af[ks] = *(const short8*)(s_a + (mt*16+ln)*200 + lq*8 + ks*32);
                float vs[4] = {0.f, 0.f, 0.f, 0.f};
#pragma unroll
                for (int p = 0; p < 2; ++p) {
                    f32x4 c = {0.f, 0.f, 0.f, 0.f};
#pragma unroll
                    for (int ks = 0; ks < 6; ++ks) c = MFMA16(af[ks], bw1[p][ks], c);
#pragma unroll
                    for (int r = 0; r < 4; ++r)
                        vs[r] += fmaxf(c[r] + b1v[p], 0.f) * w2v[p];
                }
#pragma unroll
                for (int mask = 1; mask < 16; mask <<= 1) {
#pragma unroll
                    for (int r = 0; r < 4; ++r)
                        vs[r] += __shfl_xor(vs[r], mask);
                }
                if (ln == 0) {
#pragma unroll
                    for (int r = 0; r < 4; ++r)
                        s_part[w][mt*16 + lq*4 + r] = vs[r];
                }
            }
        }
        __syncthreads();

        if (tid < 64) {
            out[gbase + tid] = s_part[0][tid] + s_part[1][tid]
                             + s_part[2][tid] + s_part[3][tid] + bias2;
        }
        __syncthreads();
    }
}

extern "C" void kernel_launch(void* const* d_in, const int* in_sizes, int n_in,
                              void* d_out, int out_size, void* d_ws, size_t ws_size,
                              hipStream_t stream)
{
    const float* x     = (const float*)d_in[0];
    const float* t     = (const float*)d_in[1];
    const float* mtok  = (const float*)d_in[2];
    const float* te_w1 = (const float*)d_in[3];
    const float* te_b1 = (const float*)d_in[4];
    const float* te_w2 = (const float*)d_in[5];
    const float* te_b2 = (const float*)d_in[6];
    const float* fpw   = (const float*)d_in[7];
    const float* fpb   = (const float*)d_in[8];
    const float* bpw   = (const float*)d_in[9];
    const float* bpb   = (const float*)d_in[10];
    const float* fwz   = (const float*)d_in[11];
    const float* fbz   = (const float*)d_in[12];
    const float* fwh   = (const float*)d_in[13];
    const float* fbh   = (const float*)d_in[14];
    const float* bwz   = (const float*)d_in[15];
    const float* bbz   = (const float*)d_in[16];
    const float* bwh   = (const float*)d_in[17];
    const float* bbh   = (const float*)d_in[18];
    const float* w1    = (const float*)d_in[19];
    const float* b1    = (const float*)d_in[20];
    const float* w2    = (const float*)d_in[21];
    const float* b2    = (const float*)d_in[22];

    const size_t per_b = 1572864ull;
    int Bg = NB;
    while ((size_t)Bg * per_b > ws_size && Bg > 1) Bg >>= 1;
    const int nG = NB / Bg;

    char* ws = (char*)d_ws;
    uint32_t*       abf  = (uint32_t*)(ws);
    uint32_t*       abb  = abf + (size_t)Bg * 64 * NL;
    unsigned short* hf   = (unsigned short*)(abb + (size_t)Bg * 64 * NL);
    unsigned short* hb   = hf + (size_t)Bg * NL * 64;

    for (int g = 0; g < nG; ++g) {
        const int b0 = g * Bg;

        prep_kernel<<<8 * Bg, 256, 0, stream>>>(
            x, t, mtok, te_w1, te_b1, te_w2, te_b2,
            fpw, fpb, bpw, bpb, fwz, fbz, fwh, fbh, bwz, bbz, bwh, bbh,
            b0, abf, abb);

        scan3_kernel<<<4 * Bg, 256, 0, stream>>>(abf, abb, hf, hb);

        head_kernel<<<8 * Bg, 256, 0, stream>>>(
            x, t, te_w1, te_b1, te_w2, te_b2,
            hf, hb, w1, b1, w2, b2, b0, (float*)d_out);
    }
}